// Round 11
// baseline (678.936 us; speedup 1.0000x reference)
//
#include <hip/hip_runtime.h>
#include <hip/hip_bf16.h>
#include <math.h>

#define N_NODES  100000
#define N_EDGES  3200000
#define N_GRAPHS 1000
#define NBKT ((N_NODES + 255) >> 8)       // 391 buckets of 256 nodes
#define BCAP 9216                         // padded bucket capacity (mean 8192, 11 sigma)
#define PCHUNK 4096
#define EPT (PCHUNK / 256)                // 16 edges per thread
#define DBIN 128                          // degree bins for node permutation

// ---------- fp32 <-> bf16 helpers ----------
__device__ __forceinline__ unsigned short f2bf(float f) {
    unsigned u = __float_as_uint(f);
    return (unsigned short)((u + 0x7FFFu + ((u >> 16) & 1u)) >> 16);   // RNE
}
// unpack a uint holding two bf16 (lo, hi) into two floats
__device__ __forceinline__ void unpack2(unsigned u, float& a, float& b) {
    a = __uint_as_float(u << 16);
    b = __uint_as_float(u & 0xFFFF0000u);
}

// ---------- detect whether integer inputs are int64 or int32 ----------
__global__ void detect_kernel(const long long* __restrict__ idx, int* __restrict__ flag) {
    int t = threadIdx.x;
    unsigned long long hi = ((unsigned long long)idx[t]) >> 32;
    unsigned long long any = __ballot(hi != 0ull);
    if (t == 0) *flag = (any == 0ull) ? 1 : 0;   // 1 => int64, 0 => int32
}

// ---------- init bucket cursors / pool / cnt / degree bins ----------
__global__ __launch_bounds__(256)
void init_kernel(unsigned* __restrict__ bcur, float* __restrict__ pool,
                 float* __restrict__ cnt, unsigned* __restrict__ dh) {
    int t = blockIdx.x * blockDim.x + threadIdx.x;
    if (t < NBKT)         bcur[t] = (unsigned)t * BCAP;
    if (t < N_GRAPHS*32)  pool[t] = 0.f;
    if (t < N_GRAPHS)     cnt[t]  = 0.f;
    if (t < DBIN)         dh[t]   = 0u;
}

// ---------- partition edges into padded bucket segments (LDS counting sort) ----------
// packed pair: (dst & 255) << 17 | src    (src < 2^17)
__global__ __launch_bounds__(256)
void partition_kernel(const int* __restrict__ idx32, const long long* __restrict__ idx64,
                      const int* __restrict__ flag,
                      unsigned* __restrict__ bcur, unsigned* __restrict__ srtp) {
    __shared__ unsigned       sbuf[PCHUNK];   // 16 KB packed pairs, chunk-sorted
    __shared__ unsigned short sbkt[PCHUNK];   // 8 KB bucket per slot
    __shared__ unsigned lhist[NBKT];
    __shared__ unsigned lscan[512];
    __shared__ unsigned gbase[NBKT];
    const int is64 = *flag;
    const int t = threadIdx.x;
    const int base = blockIdx.x * PCHUNK;
    const int nval = min(PCHUNK, N_EDGES - base);

    for (int b = t; b < NBKT; b += 256) lhist[b] = 0u;
    __syncthreads();

    unsigned pr[EPT]; unsigned short br[EPT]; unsigned short rr[EPT];
    #pragma unroll
    for (int r = 0; r < EPT; ++r) {
        int e = base + r * 256 + t;
        br[r] = 0xFFFF;
        if (e < N_EDGES) {
            int s = is64 ? (int)idx64[e]           : idx32[e];
            int d = is64 ? (int)idx64[N_EDGES + e] : idx32[N_EDGES + e];
            unsigned bk = ((unsigned)d) >> 8;
            pr[r] = (((unsigned)d & 255u) << 17) | (unsigned)s;
            br[r] = (unsigned short)bk;
            rr[r] = (unsigned short)atomicAdd(&lhist[bk], 1u);
        }
    }
    __syncthreads();

    // inclusive scan of lhist over 512 padded slots
    lscan[t]       = (t < NBKT)       ? lhist[t]       : 0u;
    lscan[t + 256] = (t + 256 < NBKT) ? lhist[t + 256] : 0u;
    __syncthreads();
    for (int off = 1; off < 512; off <<= 1) {
        unsigned v0 = (t >= off)       ? lscan[t - off]       : 0u;
        unsigned v1 = (t + 256 >= off) ? lscan[t + 256 - off] : 0u;
        __syncthreads();
        lscan[t] += v0; lscan[t + 256] += v1;
        __syncthreads();
    }

    // reserve global space per bucket (absolute position in padded layout)
    for (int b = t; b < NBKT; b += 256) {
        unsigned c = lhist[b];
        if (c) gbase[b] = atomicAdd(&bcur[b], c);
    }

    // place into chunk-sorted LDS order
    #pragma unroll
    for (int r = 0; r < EPT; ++r) {
        if (br[r] != 0xFFFF) {
            unsigned b = br[r];
            unsigned slot = lscan[b] - lhist[b] + rr[r];
            sbuf[slot] = pr[r];
            sbkt[slot] = (unsigned short)b;
        }
    }
    __syncthreads();

    // coalesced write-out per bucket run
    for (int slot = t; slot < nval; slot += 256) {
        unsigned p = sbuf[slot];
        unsigned b = sbkt[slot];
        unsigned lst = lscan[b] - lhist[b];
        srtp[gbase[b] + ((unsigned)slot - lst)] = p;
    }
}

// ---------- fused CSR build + per-row src sort + degree histogram ----------
__global__ __launch_bounds__(256)
void build_kernel(unsigned* __restrict__ srtp, const unsigned* __restrict__ bcur,
                  int* __restrict__ row_start, int* __restrict__ row_end,
                  unsigned* __restrict__ dh) {
    __shared__ unsigned sbuf[BCAP];      // 36 KB raw pairs
    __shared__ int      sdst[BCAP];      // 36 KB row-grouped srcs
    __shared__ unsigned ldeg[256];
    __shared__ unsigned lsc[256];
    __shared__ int      lcur[256];
    const int b = blockIdx.x;
    const int t = threadIdx.x;
    const int segbase = b * BCAP;
    const int cntb = min((int)bcur[b] - segbase, BCAP);

    ldeg[t] = 0u;
    __syncthreads();
    for (int e = t; e < cntb; e += 256) {
        unsigned p = srtp[segbase + e];
        sbuf[e] = p;
        atomicAdd(&ldeg[p >> 17], 1u);
    }
    __syncthreads();
    lsc[t] = ldeg[t];
    __syncthreads();
    for (int off = 1; off < 256; off <<= 1) {
        unsigned v = (t >= off) ? lsc[t - off] : 0u;
        __syncthreads();
        lsc[t] += v;
        __syncthreads();
    }
    int excl = (int)(lsc[t] - ldeg[t]);
    int node = (b << 8) + t;
    if (node < N_NODES) {
        row_start[node] = segbase + excl;
        row_end[node]   = segbase + excl + (int)ldeg[t];
        atomicAdd(&dh[min((int)ldeg[t], DBIN - 1)], 1u);
    }
    lcur[t] = excl;
    __syncthreads();
    for (int e = t; e < cntb; e += 256) {
        unsigned p = sbuf[e];
        int pos = atomicAdd(&lcur[p >> 17], 1);
        sdst[pos] = (int)(p & 0x1FFFFu);
    }
    __syncthreads();

    // per-wave bitonic sort of each row by src (len<=64; longer rows left as-is)
    const int wave = t >> 6, lane = t & 63;
    for (int n = wave; n < 256; n += 4) {
        int len = (int)ldeg[n];
        if (len < 2 || len > 64) continue;
        int lofs = (int)(lsc[n] - ldeg[n]);
        int v = (lane < len) ? sdst[lofs + lane] : 0x7FFFFFFF;
        #pragma unroll
        for (int k = 2; k <= 64; k <<= 1) {
            #pragma unroll
            for (int j = k >> 1; j > 0; j >>= 1) {
                int pv = __shfl_xor(v, j, 64);
                bool up    = (lane & k) == 0;
                bool lower = (lane & j) == 0;
                int mn = min(v, pv), mx = max(v, pv);
                v = (up == lower) ? mn : mx;
            }
        }
        if (lane < len) sdst[lofs + lane] = v;
    }
    __syncthreads();
    for (int e = t; e < cntb; e += 256)
        srtp[segbase + e] = (unsigned)sdst[e];
}

// ---------- degree-bin scan (descending degree) ----------
__global__ void degscan_kernel(const unsigned* __restrict__ dh, unsigned* __restrict__ dcur) {
    if (threadIdx.x == 0) {
        unsigned acc = 0;
        for (int d = DBIN - 1; d >= 0; --d) { dcur[d] = acc; acc += dh[d]; }
    }
}

// ---------- scatter nodes into degree-descending permutation ----------
__global__ __launch_bounds__(256)
void degscatter_kernel(const int* __restrict__ row_start, const int* __restrict__ row_end,
                       unsigned* __restrict__ dcur, int* __restrict__ perm) {
    int i = blockIdx.x * blockDim.x + threadIdx.x;
    if (i >= N_NODES) return;
    int d = min(row_end[i] - row_start[i], DBIN - 1);
    unsigned pos = atomicAdd(&dcur[d], 1u);
    perm[pos] = i;
}

// ---------- fused node linear: q = (x@Wq+bq)*scale (fp32); kv bf16 interleaved; sk fp32 ----------
// kv row layout (per node, 2*OUT bf16): [k0..3 v0..3 k4..7 v4..7 ...]
template <int IN, int OUT>
__global__ __launch_bounds__(256)
void lin_kernel(const float* __restrict__ x,
                const float* __restrict__ Wq, const float* __restrict__ bq,
                const float* __restrict__ Wk, const float* __restrict__ bk,
                const float* __restrict__ Wv, const float* __restrict__ bv,
                const float* __restrict__ Ws, const float* __restrict__ bs,
                float scale,
                float* __restrict__ q, unsigned short* __restrict__ kv,
                float* __restrict__ sk, int n)
{
    __shared__ float w[4 * IN * OUT];
    __shared__ float b[4 * OUT];
    for (int t = threadIdx.x; t < IN * OUT; t += blockDim.x) {
        w[t]            = Wq[t];
        w[IN*OUT + t]   = Wk[t];
        w[2*IN*OUT + t] = Wv[t];
        w[3*IN*OUT + t] = Ws[t];
    }
    for (int t = threadIdx.x; t < OUT; t += blockDim.x) {
        b[t]         = bq[t];
        b[OUT + t]   = bk[t];
        b[2*OUT + t] = bv[t];
        b[3*OUT + t] = bs[t];
    }
    __syncthreads();

    for (int i = blockIdx.x * blockDim.x + threadIdx.x; i < n;
         i += gridDim.x * blockDim.x) {
        float xi[IN];
        #pragma unroll
        for (int r = 0; r < IN; ++r) xi[r] = x[(size_t)i * IN + r];

        #pragma unroll
        for (int j = 0; j < OUT; ++j) {
            float aq = b[j], ak = b[OUT + j], av = b[2*OUT + j], as = b[3*OUT + j];
            #pragma unroll
            for (int r = 0; r < IN; ++r) {
                float xr = xi[r];
                aq += xr * w[r*OUT + j];
                ak += xr * w[IN*OUT + r*OUT + j];
                av += xr * w[2*IN*OUT + r*OUT + j];
                as += xr * w[3*IN*OUT + r*OUT + j];
            }
            int c = j >> 2, r4 = j & 3;
            q[(size_t)i * OUT + j]                  = aq * scale;
            kv[(size_t)i * 2 * OUT + c * 8 + r4]     = f2bf(ak);
            kv[(size_t)i * 2 * OUT + c * 8 + 4 + r4] = f2bf(av);
            sk[(size_t)i * OUT + j]                 = as;
        }
    }
}

// ---------- fused per-node attention: degree-permuted nodes, 1 load/edge/lane ----------
template <int D, bool POOL>
__global__ __launch_bounds__(256)
void fused_attn_kernel(const float* __restrict__ q, const unsigned short* __restrict__ kv,
                       const float* __restrict__ sk,
                       const int* __restrict__ row_start, const int* __restrict__ row_end,
                       const unsigned* __restrict__ sorted_src,
                       const int* __restrict__ perm,
                       const int* __restrict__ b32, const long long* __restrict__ b64,
                       const int* __restrict__ flag,
                       float* __restrict__ h, float* __restrict__ pool,
                       float* __restrict__ cnt)
{
    constexpr int L = D / 4;
    const int gpb = 256 / L;
    const int lj = threadIdx.x & (L - 1);
    int g = blockIdx.x * gpb + threadIdx.x / L;
    if (g >= N_NODES) return;
    const int i = perm[g];

    const float4 qj = *(const float4*)(q + (size_t)i * D + lj * 4);
    const int beg = row_start[i], end = row_end[i];

    float m = -INFINITY, denom = 0.f;
    float4 acc = make_float4(0.f, 0.f, 0.f, 0.f);

    if (beg < end) {
        const int last = end - 1;

        int s0 = (int)sorted_src[min(beg + 0, last)];
        int s1 = (int)sorted_src[min(beg + 1, last)];
        int s2 = (int)sorted_src[min(beg + 2, last)];
        int s3 = (int)sorted_src[min(beg + 3, last)];
        uint4 A0 = ((const uint4*)(kv + (size_t)s0 * (2 * D)))[lj];
        uint4 A1 = ((const uint4*)(kv + (size_t)s1 * (2 * D)))[lj];
        uint4 B0 = ((const uint4*)(kv + (size_t)s2 * (2 * D)))[lj];
        uint4 B1 = ((const uint4*)(kv + (size_t)s3 * (2 * D)))[lj];

        for (int e = beg; e < end; e += 4) {
            // ---- half 1: edges e, e+1 from A; refill A with e+4, e+5 ----
            {
                int sn0 = (int)sorted_src[min(e + 4, last)];
                int sn1 = (int)sorted_src[min(e + 5, last)];
                float k0,k1,k2,k3, l0,l1,l2,l3;
                unpack2(A0.x, k0, k1); unpack2(A0.y, k2, k3);
                unpack2(A1.x, l0, l1); unpack2(A1.y, l2, l3);
                float pa = k0*qj.x + k1*qj.y + k2*qj.z + k3*qj.w;
                float pb = l0*qj.x + l1*qj.y + l2*qj.z + l3*qj.w;
                #pragma unroll
                for (int off = L / 2; off; off >>= 1) {
                    pa += __shfl_xor(pa, off, L);
                    pb += __shfl_xor(pb, off, L);
                }
                if (e + 1 > last) pb = -INFINITY;
                float mn = fmaxf(m, fmaxf(pa, pb));
                float so = __expf(m - mn);
                float w0 = __expf(pa - mn);
                float w1 = __expf(pb - mn);
                float u0,u1,u2,u3, t0,t1,t2,t3;
                unpack2(A0.z, u0, u1); unpack2(A0.w, u2, u3);
                unpack2(A1.z, t0, t1); unpack2(A1.w, t2, t3);
                denom = denom * so + w0 + w1;
                acc.x = acc.x * so + w0 * u0 + w1 * t0;
                acc.y = acc.y * so + w0 * u1 + w1 * t1;
                acc.z = acc.z * so + w0 * u2 + w1 * t2;
                acc.w = acc.w * so + w0 * u3 + w1 * t3;
                m = mn;
                A0 = ((const uint4*)(kv + (size_t)sn0 * (2 * D)))[lj];
                A1 = ((const uint4*)(kv + (size_t)sn1 * (2 * D)))[lj];
            }
            // ---- half 2: edges e+2, e+3 from B; refill B with e+6, e+7 ----
            {
                int sn0 = (int)sorted_src[min(e + 6, last)];
                int sn1 = (int)sorted_src[min(e + 7, last)];
                float k0,k1,k2,k3, l0,l1,l2,l3;
                unpack2(B0.x, k0, k1); unpack2(B0.y, k2, k3);
                unpack2(B1.x, l0, l1); unpack2(B1.y, l2, l3);
                float pa = k0*qj.x + k1*qj.y + k2*qj.z + k3*qj.w;
                float pb = l0*qj.x + l1*qj.y + l2*qj.z + l3*qj.w;
                #pragma unroll
                for (int off = L / 2; off; off >>= 1) {
                    pa += __shfl_xor(pa, off, L);
                    pb += __shfl_xor(pb, off, L);
                }
                if (e + 2 > last) pa = -INFINITY;
                if (e + 3 > last) pb = -INFINITY;
                float mn = fmaxf(m, fmaxf(pa, pb));   // mn == m if both invalid
                float so = __expf(m - mn);
                float w0 = __expf(pa - mn);
                float w1 = __expf(pb - mn);
                float u0,u1,u2,u3, t0,t1,t2,t3;
                unpack2(B0.z, u0, u1); unpack2(B0.w, u2, u3);
                unpack2(B1.z, t0, t1); unpack2(B1.w, t2, t3);
                denom = denom * so + w0 + w1;
                acc.x = acc.x * so + w0 * u0 + w1 * t0;
                acc.y = acc.y * so + w0 * u1 + w1 * t1;
                acc.z = acc.z * so + w0 * u2 + w1 * t2;
                acc.w = acc.w * so + w0 * u3 + w1 * t3;
                m = mn;
                B0 = ((const uint4*)(kv + (size_t)sn0 * (2 * D)))[lj];
                B1 = ((const uint4*)(kv + (size_t)sn1 * (2 * D)))[lj];
            }
        }
    }

    float dn = 1.f / fmaxf(denom, 1e-16f);
    const float4 skv = *(const float4*)(sk + (size_t)i * D + lj * 4);
    float4 o;
    o.x = fmaxf(acc.x * dn + skv.x, 0.f);
    o.y = fmaxf(acc.y * dn + skv.y, 0.f);
    o.z = fmaxf(acc.z * dn + skv.z, 0.f);
    o.w = fmaxf(acc.w * dn + skv.w, 0.f);

    if (POOL) {
        int b = (*flag) ? (int)b64[i] : b32[i];
        float* pb = pool + b * 32 + lj * 4;
        atomicAdd(pb + 0, o.x);
        atomicAdd(pb + 1, o.y);
        atomicAdd(pb + 2, o.z);
        atomicAdd(pb + 3, o.w);
        if (lj == 0) atomicAdd(&cnt[b], 1.f);
    } else {
        *(float4*)(h + (size_t)i * D + lj * 4) = o;
    }
}

// ---------- final MLP: out = relu(mean @ Wf1 + bf1) @ Wf2 + bf2 ----------
__global__ __launch_bounds__(64)
void mlp_kernel(const float* __restrict__ pool, const float* __restrict__ cnt,
                const float* __restrict__ Wf1, const float* __restrict__ bf1,
                const float* __restrict__ Wf2, const float* __restrict__ bf2,
                float* __restrict__ out)
{
    int g = blockIdx.x;
    int h = threadIdx.x;            // 64 threads = 64 hidden units
    __shared__ float m[32];
    if (h < 32) {
        float c = fmaxf(cnt[g], 1.f);
        m[h] = pool[g * 32 + h] / c;
    }
    __syncthreads();
    float acc = bf1[h];
    #pragma unroll
    for (int r = 0; r < 32; ++r) acc += m[r] * Wf1[r * 64 + h];
    float hid = fmaxf(acc, 0.f);
    float c = hid * Wf2[h];
    #pragma unroll
    for (int off = 32; off; off >>= 1) c += __shfl_xor(c, off, 64);
    if (h == 0) out[g] = c + bf2[0];
}

extern "C" void kernel_launch(void* const* d_in, const int* in_sizes, int n_in,
                              void* d_out, int out_size, void* d_ws, size_t ws_size,
                              hipStream_t stream) {
    const float* x = (const float*)d_in[0];
    const void*  edge_index = d_in[1];
    const void*  batch      = d_in[2];
    const float* Wq1 = (const float*)d_in[3];  const float* bq1 = (const float*)d_in[4];
    const float* Wk1 = (const float*)d_in[5];  const float* bk1 = (const float*)d_in[6];
    const float* Wv1 = (const float*)d_in[7];  const float* bv1 = (const float*)d_in[8];
    const float* Ws1 = (const float*)d_in[9];  const float* bs1 = (const float*)d_in[10];
    const float* Wq2 = (const float*)d_in[11]; const float* bq2 = (const float*)d_in[12];
    const float* Wk2 = (const float*)d_in[13]; const float* bk2 = (const float*)d_in[14];
    const float* Wv2 = (const float*)d_in[15]; const float* bv2 = (const float*)d_in[16];
    const float* Ws2 = (const float*)d_in[17]; const float* bs2 = (const float*)d_in[18];
    const float* Wf1 = (const float*)d_in[19]; const float* bf1 = (const float*)d_in[20];
    const float* Wf2 = (const float*)d_in[21]; const float* bf2 = (const float*)d_in[22];
    float* out = (float*)d_out;

    // ---------------- workspace layout (~60 MB) ----------------
    char* ws = (char*)d_ws;
    size_t off = 0;
    auto carve = [&](size_t bytes) {
        char* p = ws + off;
        off = (off + bytes + 255) & ~(size_t)255;
        return p;
    };
    int*            flag     = (int*)            carve(16);
    int*            row_start= (int*)            carve((size_t)N_NODES * 4);
    int*            row_end  = (int*)            carve((size_t)N_NODES * 4);
    unsigned*       bcur     = (unsigned*)       carve((size_t)NBKT * 4);
    float*          pool     = (float*)          carve((size_t)N_GRAPHS * 32 * 4);
    float*          cnt      = (float*)          carve((size_t)N_GRAPHS * 4);
    unsigned*       dh       = (unsigned*)       carve((size_t)DBIN * 4);
    unsigned*       dcur     = (unsigned*)       carve((size_t)DBIN * 4);
    int*            perm     = (int*)            carve((size_t)N_NODES * 4);
    unsigned*       srtp     = (unsigned*)       carve((size_t)NBKT * BCAP * 4);  // padded pairs -> sorted srcs
    float*          qb       = (float*)          carve((size_t)N_NODES * 32 * 4);
    unsigned short* kvb      = (unsigned short*) carve((size_t)N_NODES * 64 * 2);
    float*          skb      = (float*)          carve((size_t)N_NODES * 32 * 4);
    float*          h1       = (float*)          carve((size_t)N_NODES * 16 * 4);
    (void)ws_size; (void)in_sizes; (void)n_in; (void)out_size;

    const int* ei32 = (const int*)edge_index;
    const long long* ei64 = (const long long*)edge_index;
    const int* b32 = (const int*)batch;
    const long long* b64 = (const long long*)batch;

    const dim3 blk(256);

    // ---- CSR build: padded buckets, single partition pass, fused build+rowsort ----
    detect_kernel<<<1, 64, 0, stream>>>(ei64, flag);
    init_kernel<<<(N_GRAPHS * 32 + 255) / 256, blk, 0, stream>>>(bcur, pool, cnt, dh);
    partition_kernel<<<(N_EDGES + PCHUNK - 1) / PCHUNK, blk, 0, stream>>>(
        ei32, ei64, flag, bcur, srtp);
    build_kernel<<<NBKT, blk, 0, stream>>>(srtp, bcur, row_start, row_end, dh);
    degscan_kernel<<<1, 64, 0, stream>>>(dh, dcur);
    degscatter_kernel<<<(N_NODES + 255) / 256, blk, 0, stream>>>(
        row_start, row_end, dcur, perm);

    // ---- layer 1 (11 -> 16): L=4 lanes/node, 64 nodes/block ----
    lin_kernel<11, 16><<<(N_NODES + 255) / 256, blk, 0, stream>>>(
        x, Wq1, bq1, Wk1, bk1, Wv1, bv1, Ws1, bs1, 0.25f,
        qb, kvb, skb, N_NODES);
    fused_attn_kernel<16, false><<<(N_NODES + 63) / 64, blk, 0, stream>>>(
        qb, kvb, skb, row_start, row_end, srtp, perm, b32, b64, flag, h1, pool, cnt);

    // ---- layer 2 (16 -> 32): L=8 lanes/node, 32 nodes/block; pooling fused ----
    lin_kernel<16, 32><<<(N_NODES + 255) / 256, blk, 0, stream>>>(
        h1, Wq2, bq2, Wk2, bk2, Wv2, bv2, Ws2, bs2, 0.17677669529663688f,
        qb, kvb, skb, N_NODES);
    fused_attn_kernel<32, true><<<(N_NODES + 31) / 32, blk, 0, stream>>>(
        qb, kvb, skb, row_start, row_end, srtp, perm, b32, b64, flag, nullptr, pool, cnt);

    // ---- MLP head ----
    mlp_kernel<<<N_GRAPHS, 64, 0, stream>>>(pool, cnt, Wf1, bf1, Wf2, bf2, out);
}

// Round 12
// 352.107 us; speedup vs baseline: 1.9282x; 1.9282x over previous
//
#include <hip/hip_runtime.h>
#include <hip/hip_bf16.h>
#include <math.h>

#define N_NODES  100000
#define N_EDGES  3200000
#define N_GRAPHS 1000
#define NBKT ((N_NODES + 255) >> 8)       // 391 buckets of 256 nodes
#define BCAP 9216                         // padded bucket capacity (mean 8192, 11 sigma)
#define PCHUNK 4096
#define EPT (PCHUNK / 256)                // 16 edges per thread
#define DBIN 128                          // degree bins for node permutation

// ---------- fp32 <-> bf16 helpers ----------
__device__ __forceinline__ unsigned short f2bf(float f) {
    unsigned u = __float_as_uint(f);
    return (unsigned short)((u + 0x7FFFu + ((u >> 16) & 1u)) >> 16);   // RNE
}
// unpack a uint holding two bf16 (lo, hi) into two floats
__device__ __forceinline__ void unpack2(unsigned u, float& a, float& b) {
    a = __uint_as_float(u << 16);
    b = __uint_as_float(u & 0xFFFF0000u);
}

// ---------- detect whether integer inputs are int64 or int32 ----------
__global__ void detect_kernel(const long long* __restrict__ idx, int* __restrict__ flag) {
    int t = threadIdx.x;
    unsigned long long hi = ((unsigned long long)idx[t]) >> 32;
    unsigned long long any = __ballot(hi != 0ull);
    if (t == 0) *flag = (any == 0ull) ? 1 : 0;   // 1 => int64, 0 => int32
}

// ---------- init bucket cursors / pool / cnt / degree bins ----------
__global__ __launch_bounds__(256)
void init_kernel(unsigned* __restrict__ bcur, float* __restrict__ pool,
                 float* __restrict__ cnt, unsigned* __restrict__ dh) {
    int t = blockIdx.x * blockDim.x + threadIdx.x;
    if (t < NBKT)         bcur[t] = (unsigned)t * BCAP;
    if (t < N_GRAPHS*32)  pool[t] = 0.f;
    if (t < N_GRAPHS)     cnt[t]  = 0.f;
    if (t < DBIN)         dh[t]   = 0u;
}

// ---------- partition edges into padded bucket segments (LDS counting sort) ----------
// packed pair: (dst & 255) << 17 | src    (src < 2^17)
__global__ __launch_bounds__(256)
void partition_kernel(const int* __restrict__ idx32, const long long* __restrict__ idx64,
                      const int* __restrict__ flag,
                      unsigned* __restrict__ bcur, unsigned* __restrict__ srtp) {
    __shared__ unsigned       sbuf[PCHUNK];   // 16 KB packed pairs, chunk-sorted
    __shared__ unsigned short sbkt[PCHUNK];   // 8 KB bucket per slot
    __shared__ unsigned lhist[NBKT];
    __shared__ unsigned lscan[512];
    __shared__ unsigned gbase[NBKT];
    const int is64 = *flag;
    const int t = threadIdx.x;
    const int base = blockIdx.x * PCHUNK;
    const int nval = min(PCHUNK, N_EDGES - base);

    for (int b = t; b < NBKT; b += 256) lhist[b] = 0u;
    __syncthreads();

    unsigned pr[EPT]; unsigned short br[EPT]; unsigned short rr[EPT];
    #pragma unroll
    for (int r = 0; r < EPT; ++r) {
        int e = base + r * 256 + t;
        br[r] = 0xFFFF;
        if (e < N_EDGES) {
            int s = is64 ? (int)idx64[e]           : idx32[e];
            int d = is64 ? (int)idx64[N_EDGES + e] : idx32[N_EDGES + e];
            unsigned bk = ((unsigned)d) >> 8;
            pr[r] = (((unsigned)d & 255u) << 17) | (unsigned)s;
            br[r] = (unsigned short)bk;
            rr[r] = (unsigned short)atomicAdd(&lhist[bk], 1u);
        }
    }
    __syncthreads();

    // inclusive scan of lhist over 512 padded slots
    lscan[t]       = (t < NBKT)       ? lhist[t]       : 0u;
    lscan[t + 256] = (t + 256 < NBKT) ? lhist[t + 256] : 0u;
    __syncthreads();
    for (int off = 1; off < 512; off <<= 1) {
        unsigned v0 = (t >= off)       ? lscan[t - off]       : 0u;
        unsigned v1 = (t + 256 >= off) ? lscan[t + 256 - off] : 0u;
        __syncthreads();
        lscan[t] += v0; lscan[t + 256] += v1;
        __syncthreads();
    }

    // reserve global space per bucket (absolute position in padded layout)
    for (int b = t; b < NBKT; b += 256) {
        unsigned c = lhist[b];
        if (c) gbase[b] = atomicAdd(&bcur[b], c);
    }

    // place into chunk-sorted LDS order
    #pragma unroll
    for (int r = 0; r < EPT; ++r) {
        if (br[r] != 0xFFFF) {
            unsigned b = br[r];
            unsigned slot = lscan[b] - lhist[b] + rr[r];
            sbuf[slot] = pr[r];
            sbkt[slot] = (unsigned short)b;
        }
    }
    __syncthreads();

    // coalesced write-out per bucket run
    for (int slot = t; slot < nval; slot += 256) {
        unsigned p = sbuf[slot];
        unsigned b = sbkt[slot];
        unsigned lst = lscan[b] - lhist[b];
        srtp[gbase[b] + ((unsigned)slot - lst)] = p;
    }
}

// ---------- fused CSR build + per-row src sort + LDS-aggregated degree histogram ----------
__global__ __launch_bounds__(256)
void build_kernel(unsigned* __restrict__ srtp, const unsigned* __restrict__ bcur,
                  int* __restrict__ row_start, int* __restrict__ row_end,
                  unsigned* __restrict__ dh) {
    __shared__ unsigned sbuf[BCAP];      // 36 KB raw pairs
    __shared__ int      sdst[BCAP];      // 36 KB row-grouped srcs
    __shared__ unsigned ldeg[256];
    __shared__ unsigned lsc[256];
    __shared__ int      lcur[256];
    __shared__ unsigned ldh[DBIN];       // block-local degree histogram
    const int b = blockIdx.x;
    const int t = threadIdx.x;
    const int segbase = b * BCAP;
    const int cntb = min((int)bcur[b] - segbase, BCAP);

    ldeg[t] = 0u;
    if (t < DBIN) ldh[t] = 0u;
    __syncthreads();
    for (int e = t; e < cntb; e += 256) {
        unsigned p = srtp[segbase + e];
        sbuf[e] = p;
        atomicAdd(&ldeg[p >> 17], 1u);
    }
    __syncthreads();
    lsc[t] = ldeg[t];
    __syncthreads();
    for (int off = 1; off < 256; off <<= 1) {
        unsigned v = (t >= off) ? lsc[t - off] : 0u;
        __syncthreads();
        lsc[t] += v;
        __syncthreads();
    }
    int excl = (int)(lsc[t] - ldeg[t]);
    int node = (b << 8) + t;
    if (node < N_NODES) {
        row_start[node] = segbase + excl;
        row_end[node]   = segbase + excl + (int)ldeg[t];
        atomicAdd(&ldh[min((int)ldeg[t], DBIN - 1)], 1u);   // LDS, not global
    }
    lcur[t] = excl;
    __syncthreads();
    // merge block histogram to global (<=128 aggregated atomics per block)
    if (t < DBIN && ldh[t]) atomicAdd(&dh[t], ldh[t]);
    for (int e = t; e < cntb; e += 256) {
        unsigned p = sbuf[e];
        int pos = atomicAdd(&lcur[p >> 17], 1);
        sdst[pos] = (int)(p & 0x1FFFFu);
    }
    __syncthreads();

    // per-wave bitonic sort of each row by src (len<=64; longer rows left as-is)
    const int wave = t >> 6, lane = t & 63;
    for (int n = wave; n < 256; n += 4) {
        int len = (int)ldeg[n];
        if (len < 2 || len > 64) continue;
        int lofs = (int)(lsc[n] - ldeg[n]);
        int v = (lane < len) ? sdst[lofs + lane] : 0x7FFFFFFF;
        #pragma unroll
        for (int k = 2; k <= 64; k <<= 1) {
            #pragma unroll
            for (int j = k >> 1; j > 0; j >>= 1) {
                int pv = __shfl_xor(v, j, 64);
                bool up    = (lane & k) == 0;
                bool lower = (lane & j) == 0;
                int mn = min(v, pv), mx = max(v, pv);
                v = (up == lower) ? mn : mx;
            }
        }
        if (lane < len) sdst[lofs + lane] = v;
    }
    __syncthreads();
    for (int e = t; e < cntb; e += 256)
        srtp[segbase + e] = (unsigned)sdst[e];
}

// ---------- degree-bin scan (descending degree) ----------
__global__ void degscan_kernel(const unsigned* __restrict__ dh, unsigned* __restrict__ dcur) {
    if (threadIdx.x == 0) {
        unsigned acc = 0;
        for (int d = DBIN - 1; d >= 0; --d) { dcur[d] = acc; acc += dh[d]; }
    }
}

// ---------- scatter nodes into degree-descending permutation (block-aggregated) ----------
__global__ __launch_bounds__(256)
void degscatter_kernel(const int* __restrict__ row_start, const int* __restrict__ row_end,
                       unsigned* __restrict__ dcur, int* __restrict__ perm) {
    __shared__ unsigned lh[DBIN];
    __shared__ unsigned lbase[DBIN];
    const int t = threadIdx.x;
    const int i = blockIdx.x * 256 + t;
    if (t < DBIN) lh[t] = 0u;
    __syncthreads();
    int d = -1; unsigned rank = 0;
    if (i < N_NODES) {
        d = min(row_end[i] - row_start[i], DBIN - 1);
        rank = atomicAdd(&lh[d], 1u);          // LDS rank within block's bin
    }
    __syncthreads();
    if (t < DBIN) {
        unsigned c = lh[t];
        lbase[t] = c ? atomicAdd(&dcur[t], c) : 0u;   // one global atomic per nonzero bin
    }
    __syncthreads();
    if (i < N_NODES) perm[lbase[d] + rank] = i;
}

// ---------- fused node linear: q = (x@Wq+bq)*scale (fp32); kv bf16 interleaved; sk fp32 ----------
// kv row layout (per node, 2*OUT bf16): [k0..3 v0..3 k4..7 v4..7 ...]
template <int IN, int OUT>
__global__ __launch_bounds__(256)
void lin_kernel(const float* __restrict__ x,
                const float* __restrict__ Wq, const float* __restrict__ bq,
                const float* __restrict__ Wk, const float* __restrict__ bk,
                const float* __restrict__ Wv, const float* __restrict__ bv,
                const float* __restrict__ Ws, const float* __restrict__ bs,
                float scale,
                float* __restrict__ q, unsigned short* __restrict__ kv,
                float* __restrict__ sk, int n)
{
    __shared__ float w[4 * IN * OUT];
    __shared__ float b[4 * OUT];
    for (int t = threadIdx.x; t < IN * OUT; t += blockDim.x) {
        w[t]            = Wq[t];
        w[IN*OUT + t]   = Wk[t];
        w[2*IN*OUT + t] = Wv[t];
        w[3*IN*OUT + t] = Ws[t];
    }
    for (int t = threadIdx.x; t < OUT; t += blockDim.x) {
        b[t]         = bq[t];
        b[OUT + t]   = bk[t];
        b[2*OUT + t] = bv[t];
        b[3*OUT + t] = bs[t];
    }
    __syncthreads();

    for (int i = blockIdx.x * blockDim.x + threadIdx.x; i < n;
         i += gridDim.x * blockDim.x) {
        float xi[IN];
        #pragma unroll
        for (int r = 0; r < IN; ++r) xi[r] = x[(size_t)i * IN + r];

        #pragma unroll
        for (int j = 0; j < OUT; ++j) {
            float aq = b[j], ak = b[OUT + j], av = b[2*OUT + j], as = b[3*OUT + j];
            #pragma unroll
            for (int r = 0; r < IN; ++r) {
                float xr = xi[r];
                aq += xr * w[r*OUT + j];
                ak += xr * w[IN*OUT + r*OUT + j];
                av += xr * w[2*IN*OUT + r*OUT + j];
                as += xr * w[3*IN*OUT + r*OUT + j];
            }
            int c = j >> 2, r4 = j & 3;
            q[(size_t)i * OUT + j]                  = aq * scale;
            kv[(size_t)i * 2 * OUT + c * 8 + r4]     = f2bf(ak);
            kv[(size_t)i * 2 * OUT + c * 8 + 4 + r4] = f2bf(av);
            sk[(size_t)i * OUT + j]                 = as;
        }
    }
}

// ---------- fused per-node attention: degree-permuted nodes, 1 load/edge/lane ----------
template <int D, bool POOL>
__global__ __launch_bounds__(256)
void fused_attn_kernel(const float* __restrict__ q, const unsigned short* __restrict__ kv,
                       const float* __restrict__ sk,
                       const int* __restrict__ row_start, const int* __restrict__ row_end,
                       const unsigned* __restrict__ sorted_src,
                       const int* __restrict__ perm,
                       const int* __restrict__ b32, const long long* __restrict__ b64,
                       const int* __restrict__ flag,
                       float* __restrict__ h, float* __restrict__ pool,
                       float* __restrict__ cnt)
{
    constexpr int L = D / 4;
    const int gpb = 256 / L;
    const int lj = threadIdx.x & (L - 1);
    int g = blockIdx.x * gpb + threadIdx.x / L;
    if (g >= N_NODES) return;
    const int i = perm[g];

    const float4 qj = *(const float4*)(q + (size_t)i * D + lj * 4);
    const int beg = row_start[i], end = row_end[i];

    float m = -INFINITY, denom = 0.f;
    float4 acc = make_float4(0.f, 0.f, 0.f, 0.f);

    if (beg < end) {
        const int last = end - 1;

        int s0 = (int)sorted_src[min(beg + 0, last)];
        int s1 = (int)sorted_src[min(beg + 1, last)];
        int s2 = (int)sorted_src[min(beg + 2, last)];
        int s3 = (int)sorted_src[min(beg + 3, last)];
        uint4 A0 = ((const uint4*)(kv + (size_t)s0 * (2 * D)))[lj];
        uint4 A1 = ((const uint4*)(kv + (size_t)s1 * (2 * D)))[lj];
        uint4 B0 = ((const uint4*)(kv + (size_t)s2 * (2 * D)))[lj];
        uint4 B1 = ((const uint4*)(kv + (size_t)s3 * (2 * D)))[lj];

        for (int e = beg; e < end; e += 4) {
            // ---- half 1: edges e, e+1 from A; refill A with e+4, e+5 ----
            {
                int sn0 = (int)sorted_src[min(e + 4, last)];
                int sn1 = (int)sorted_src[min(e + 5, last)];
                float k0,k1,k2,k3, l0,l1,l2,l3;
                unpack2(A0.x, k0, k1); unpack2(A0.y, k2, k3);
                unpack2(A1.x, l0, l1); unpack2(A1.y, l2, l3);
                float pa = k0*qj.x + k1*qj.y + k2*qj.z + k3*qj.w;
                float pb = l0*qj.x + l1*qj.y + l2*qj.z + l3*qj.w;
                #pragma unroll
                for (int off = L / 2; off; off >>= 1) {
                    pa += __shfl_xor(pa, off, L);
                    pb += __shfl_xor(pb, off, L);
                }
                if (e + 1 > last) pb = -INFINITY;
                float mn = fmaxf(m, fmaxf(pa, pb));
                float so = __expf(m - mn);
                float w0 = __expf(pa - mn);
                float w1 = __expf(pb - mn);
                float u0,u1,u2,u3, t0,t1,t2,t3;
                unpack2(A0.z, u0, u1); unpack2(A0.w, u2, u3);
                unpack2(A1.z, t0, t1); unpack2(A1.w, t2, t3);
                denom = denom * so + w0 + w1;
                acc.x = acc.x * so + w0 * u0 + w1 * t0;
                acc.y = acc.y * so + w0 * u1 + w1 * t1;
                acc.z = acc.z * so + w0 * u2 + w1 * t2;
                acc.w = acc.w * so + w0 * u3 + w1 * t3;
                m = mn;
                A0 = ((const uint4*)(kv + (size_t)sn0 * (2 * D)))[lj];
                A1 = ((const uint4*)(kv + (size_t)sn1 * (2 * D)))[lj];
            }
            // ---- half 2: edges e+2, e+3 from B; refill B with e+6, e+7 ----
            {
                int sn0 = (int)sorted_src[min(e + 6, last)];
                int sn1 = (int)sorted_src[min(e + 7, last)];
                float k0,k1,k2,k3, l0,l1,l2,l3;
                unpack2(B0.x, k0, k1); unpack2(B0.y, k2, k3);
                unpack2(B1.x, l0, l1); unpack2(B1.y, l2, l3);
                float pa = k0*qj.x + k1*qj.y + k2*qj.z + k3*qj.w;
                float pb = l0*qj.x + l1*qj.y + l2*qj.z + l3*qj.w;
                #pragma unroll
                for (int off = L / 2; off; off >>= 1) {
                    pa += __shfl_xor(pa, off, L);
                    pb += __shfl_xor(pb, off, L);
                }
                if (e + 2 > last) pa = -INFINITY;
                if (e + 3 > last) pb = -INFINITY;
                float mn = fmaxf(m, fmaxf(pa, pb));   // mn == m if both invalid
                float so = __expf(m - mn);
                float w0 = __expf(pa - mn);
                float w1 = __expf(pb - mn);
                float u0,u1,u2,u3, t0,t1,t2,t3;
                unpack2(B0.z, u0, u1); unpack2(B0.w, u2, u3);
                unpack2(B1.z, t0, t1); unpack2(B1.w, t2, t3);
                denom = denom * so + w0 + w1;
                acc.x = acc.x * so + w0 * u0 + w1 * t0;
                acc.y = acc.y * so + w0 * u1 + w1 * t1;
                acc.z = acc.z * so + w0 * u2 + w1 * t2;
                acc.w = acc.w * so + w0 * u3 + w1 * t3;
                m = mn;
                B0 = ((const uint4*)(kv + (size_t)sn0 * (2 * D)))[lj];
                B1 = ((const uint4*)(kv + (size_t)sn1 * (2 * D)))[lj];
            }
        }
    }

    float dn = 1.f / fmaxf(denom, 1e-16f);
    const float4 skv = *(const float4*)(sk + (size_t)i * D + lj * 4);
    float4 o;
    o.x = fmaxf(acc.x * dn + skv.x, 0.f);
    o.y = fmaxf(acc.y * dn + skv.y, 0.f);
    o.z = fmaxf(acc.z * dn + skv.z, 0.f);
    o.w = fmaxf(acc.w * dn + skv.w, 0.f);

    if (POOL) {
        int b = (*flag) ? (int)b64[i] : b32[i];
        float* pb = pool + b * 32 + lj * 4;
        atomicAdd(pb + 0, o.x);
        atomicAdd(pb + 1, o.y);
        atomicAdd(pb + 2, o.z);
        atomicAdd(pb + 3, o.w);
        if (lj == 0) atomicAdd(&cnt[b], 1.f);
    } else {
        *(float4*)(h + (size_t)i * D + lj * 4) = o;
    }
}

// ---------- final MLP: out = relu(mean @ Wf1 + bf1) @ Wf2 + bf2 ----------
__global__ __launch_bounds__(64)
void mlp_kernel(const float* __restrict__ pool, const float* __restrict__ cnt,
                const float* __restrict__ Wf1, const float* __restrict__ bf1,
                const float* __restrict__ Wf2, const float* __restrict__ bf2,
                float* __restrict__ out)
{
    int g = blockIdx.x;
    int h = threadIdx.x;            // 64 threads = 64 hidden units
    __shared__ float m[32];
    if (h < 32) {
        float c = fmaxf(cnt[g], 1.f);
        m[h] = pool[g * 32 + h] / c;
    }
    __syncthreads();
    float acc = bf1[h];
    #pragma unroll
    for (int r = 0; r < 32; ++r) acc += m[r] * Wf1[r * 64 + h];
    float hid = fmaxf(acc, 0.f);
    float c = hid * Wf2[h];
    #pragma unroll
    for (int off = 32; off; off >>= 1) c += __shfl_xor(c, off, 64);
    if (h == 0) out[g] = c + bf2[0];
}

extern "C" void kernel_launch(void* const* d_in, const int* in_sizes, int n_in,
                              void* d_out, int out_size, void* d_ws, size_t ws_size,
                              hipStream_t stream) {
    const float* x = (const float*)d_in[0];
    const void*  edge_index = d_in[1];
    const void*  batch      = d_in[2];
    const float* Wq1 = (const float*)d_in[3];  const float* bq1 = (const float*)d_in[4];
    const float* Wk1 = (const float*)d_in[5];  const float* bk1 = (const float*)d_in[6];
    const float* Wv1 = (const float*)d_in[7];  const float* bv1 = (const float*)d_in[8];
    const float* Ws1 = (const float*)d_in[9];  const float* bs1 = (const float*)d_in[10];
    const float* Wq2 = (const float*)d_in[11]; const float* bq2 = (const float*)d_in[12];
    const float* Wk2 = (const float*)d_in[13]; const float* bk2 = (const float*)d_in[14];
    const float* Wv2 = (const float*)d_in[15]; const float* bv2 = (const float*)d_in[16];
    const float* Ws2 = (const float*)d_in[17]; const float* bs2 = (const float*)d_in[18];
    const float* Wf1 = (const float*)d_in[19]; const float* bf1 = (const float*)d_in[20];
    const float* Wf2 = (const float*)d_in[21]; const float* bf2 = (const float*)d_in[22];
    float* out = (float*)d_out;

    // ---------------- workspace layout (~60 MB) ----------------
    char* ws = (char*)d_ws;
    size_t off = 0;
    auto carve = [&](size_t bytes) {
        char* p = ws + off;
        off = (off + bytes + 255) & ~(size_t)255;
        return p;
    };
    int*            flag     = (int*)            carve(16);
    int*            row_start= (int*)            carve((size_t)N_NODES * 4);
    int*            row_end  = (int*)            carve((size_t)N_NODES * 4);
    unsigned*       bcur     = (unsigned*)       carve((size_t)NBKT * 4);
    float*          pool     = (float*)          carve((size_t)N_GRAPHS * 32 * 4);
    float*          cnt      = (float*)          carve((size_t)N_GRAPHS * 4);
    unsigned*       dh       = (unsigned*)       carve((size_t)DBIN * 4);
    unsigned*       dcur     = (unsigned*)       carve((size_t)DBIN * 4);
    int*            perm     = (int*)            carve((size_t)N_NODES * 4);
    unsigned*       srtp     = (unsigned*)       carve((size_t)NBKT * BCAP * 4);  // padded pairs -> sorted srcs
    float*          qb       = (float*)          carve((size_t)N_NODES * 32 * 4);
    unsigned short* kvb      = (unsigned short*) carve((size_t)N_NODES * 64 * 2);
    float*          skb      = (float*)          carve((size_t)N_NODES * 32 * 4);
    float*          h1       = (float*)          carve((size_t)N_NODES * 16 * 4);
    (void)ws_size; (void)in_sizes; (void)n_in; (void)out_size;

    const int* ei32 = (const int*)edge_index;
    const long long* ei64 = (const long long*)edge_index;
    const int* b32 = (const int*)batch;
    const long long* b64 = (const long long*)batch;

    const dim3 blk(256);

    // ---- CSR build: padded buckets, single partition pass, fused build+rowsort ----
    detect_kernel<<<1, 64, 0, stream>>>(ei64, flag);
    init_kernel<<<(N_GRAPHS * 32 + 255) / 256, blk, 0, stream>>>(bcur, pool, cnt, dh);
    partition_kernel<<<(N_EDGES + PCHUNK - 1) / PCHUNK, blk, 0, stream>>>(
        ei32, ei64, flag, bcur, srtp);
    build_kernel<<<NBKT, blk, 0, stream>>>(srtp, bcur, row_start, row_end, dh);
    degscan_kernel<<<1, 64, 0, stream>>>(dh, dcur);
    degscatter_kernel<<<(N_NODES + 255) / 256, blk, 0, stream>>>(
        row_start, row_end, dcur, perm);

    // ---- layer 1 (11 -> 16): L=4 lanes/node, 64 nodes/block ----
    lin_kernel<11, 16><<<(N_NODES + 255) / 256, blk, 0, stream>>>(
        x, Wq1, bq1, Wk1, bk1, Wv1, bv1, Ws1, bs1, 0.25f,
        qb, kvb, skb, N_NODES);
    fused_attn_kernel<16, false><<<(N_NODES + 63) / 64, blk, 0, stream>>>(
        qb, kvb, skb, row_start, row_end, srtp, perm, b32, b64, flag, h1, pool, cnt);

    // ---- layer 2 (16 -> 32): L=8 lanes/node, 32 nodes/block; pooling fused ----
    lin_kernel<16, 32><<<(N_NODES + 255) / 256, blk, 0, stream>>>(
        h1, Wq2, bq2, Wk2, bk2, Wv2, bv2, Ws2, bs2, 0.17677669529663688f,
        qb, kvb, skb, N_NODES);
    fused_attn_kernel<32, true><<<(N_NODES + 31) / 32, blk, 0, stream>>>(
        qb, kvb, skb, row_start, row_end, srtp, perm, b32, b64, flag, nullptr, pool, cnt);

    // ---- MLP head ----
    mlp_kernel<<<N_GRAPHS, 64, 0, stream>>>(pool, cnt, Wf1, bf1, Wf2, bf2, out);
}

// Round 13
// 351.127 us; speedup vs baseline: 1.9336x; 1.0028x over previous
//
#include <hip/hip_runtime.h>
#include <hip/hip_bf16.h>
#include <math.h>

#define N_NODES  100000
#define N_EDGES  3200000
#define N_GRAPHS 1000
#define NBKT ((N_NODES + 255) >> 8)       // 391 buckets of 256 nodes
#define BCAP 9216                         // padded bucket capacity (mean 8192, 11 sigma)
#define PCHUNK 4096
#define EPT (PCHUNK / 256)                // 16 edges per thread
#define DBIN 128                          // degree bins for node permutation

// ---------- fp32 <-> bf16 helpers ----------
__device__ __forceinline__ unsigned short f2bf(float f) {
    unsigned u = __float_as_uint(f);
    return (unsigned short)((u + 0x7FFFu + ((u >> 16) & 1u)) >> 16);   // RNE
}
// unpack a uint holding two bf16 (lo, hi) into two floats
__device__ __forceinline__ void unpack2(unsigned u, float& a, float& b) {
    a = __uint_as_float(u << 16);
    b = __uint_as_float(u & 0xFFFF0000u);
}

// ---------- detect whether integer inputs are int64 or int32 ----------
__global__ void detect_kernel(const long long* __restrict__ idx, int* __restrict__ flag) {
    int t = threadIdx.x;
    unsigned long long hi = ((unsigned long long)idx[t]) >> 32;
    unsigned long long any = __ballot(hi != 0ull);
    if (t == 0) *flag = (any == 0ull) ? 1 : 0;   // 1 => int64, 0 => int32
}

// ---------- init bucket cursors / pool / cnt / degree bins ----------
__global__ __launch_bounds__(256)
void init_kernel(unsigned* __restrict__ bcur, float* __restrict__ pool,
                 float* __restrict__ cnt, unsigned* __restrict__ dh) {
    int t = blockIdx.x * blockDim.x + threadIdx.x;
    if (t < NBKT)         bcur[t] = (unsigned)t * BCAP;
    if (t < N_GRAPHS*32)  pool[t] = 0.f;
    if (t < N_GRAPHS)     cnt[t]  = 0.f;
    if (t < DBIN)         dh[t]   = 0u;
}

// ---------- partition edges into padded bucket segments (LDS counting sort) ----------
// packed pair: (dst & 255) << 17 | src    (src < 2^17)
__global__ __launch_bounds__(256)
void partition_kernel(const int* __restrict__ idx32, const long long* __restrict__ idx64,
                      const int* __restrict__ flag,
                      unsigned* __restrict__ bcur, unsigned* __restrict__ srtp) {
    __shared__ unsigned       sbuf[PCHUNK];   // 16 KB packed pairs, chunk-sorted
    __shared__ unsigned short sbkt[PCHUNK];   // 8 KB bucket per slot
    __shared__ unsigned lhist[NBKT];
    __shared__ unsigned lscan[512];
    __shared__ unsigned gbase[NBKT];
    const int is64 = *flag;
    const int t = threadIdx.x;
    const int base = blockIdx.x * PCHUNK;
    const int nval = min(PCHUNK, N_EDGES - base);

    for (int b = t; b < NBKT; b += 256) lhist[b] = 0u;
    __syncthreads();

    unsigned pr[EPT]; unsigned short br[EPT]; unsigned short rr[EPT];
    #pragma unroll
    for (int r = 0; r < EPT; ++r) {
        int e = base + r * 256 + t;
        br[r] = 0xFFFF;
        if (e < N_EDGES) {
            int s = is64 ? (int)idx64[e]           : idx32[e];
            int d = is64 ? (int)idx64[N_EDGES + e] : idx32[N_EDGES + e];
            unsigned bk = ((unsigned)d) >> 8;
            pr[r] = (((unsigned)d & 255u) << 17) | (unsigned)s;
            br[r] = (unsigned short)bk;
            rr[r] = (unsigned short)atomicAdd(&lhist[bk], 1u);
        }
    }
    __syncthreads();

    // inclusive scan of lhist over 512 padded slots
    lscan[t]       = (t < NBKT)       ? lhist[t]       : 0u;
    lscan[t + 256] = (t + 256 < NBKT) ? lhist[t + 256] : 0u;
    __syncthreads();
    for (int off = 1; off < 512; off <<= 1) {
        unsigned v0 = (t >= off)       ? lscan[t - off]       : 0u;
        unsigned v1 = (t + 256 >= off) ? lscan[t + 256 - off] : 0u;
        __syncthreads();
        lscan[t] += v0; lscan[t + 256] += v1;
        __syncthreads();
    }

    // reserve global space per bucket (absolute position in padded layout)
    for (int b = t; b < NBKT; b += 256) {
        unsigned c = lhist[b];
        if (c) gbase[b] = atomicAdd(&bcur[b], c);
    }

    // place into chunk-sorted LDS order
    #pragma unroll
    for (int r = 0; r < EPT; ++r) {
        if (br[r] != 0xFFFF) {
            unsigned b = br[r];
            unsigned slot = lscan[b] - lhist[b] + rr[r];
            sbuf[slot] = pr[r];
            sbkt[slot] = (unsigned short)b;
        }
    }
    __syncthreads();

    // coalesced write-out per bucket run
    for (int slot = t; slot < nval; slot += 256) {
        unsigned p = sbuf[slot];
        unsigned b = sbkt[slot];
        unsigned lst = lscan[b] - lhist[b];
        srtp[gbase[b] + ((unsigned)slot - lst)] = p;
    }
}

// ---------- fused CSR build + per-row src sort + LDS-aggregated degree histogram ----------
__global__ __launch_bounds__(256)
void build_kernel(unsigned* __restrict__ srtp, const unsigned* __restrict__ bcur,
                  int* __restrict__ row_start, int* __restrict__ row_end,
                  unsigned* __restrict__ dh) {
    __shared__ unsigned sbuf[BCAP];      // 36 KB raw pairs
    __shared__ int      sdst[BCAP];      // 36 KB row-grouped srcs
    __shared__ unsigned ldeg[256];
    __shared__ unsigned lsc[256];
    __shared__ int      lcur[256];
    __shared__ unsigned ldh[DBIN];       // block-local degree histogram
    const int b = blockIdx.x;
    const int t = threadIdx.x;
    const int segbase = b * BCAP;
    const int cntb = min((int)bcur[b] - segbase, BCAP);

    ldeg[t] = 0u;
    if (t < DBIN) ldh[t] = 0u;
    __syncthreads();
    for (int e = t; e < cntb; e += 256) {
        unsigned p = srtp[segbase + e];
        sbuf[e] = p;
        atomicAdd(&ldeg[p >> 17], 1u);
    }
    __syncthreads();
    lsc[t] = ldeg[t];
    __syncthreads();
    for (int off = 1; off < 256; off <<= 1) {
        unsigned v = (t >= off) ? lsc[t - off] : 0u;
        __syncthreads();
        lsc[t] += v;
        __syncthreads();
    }
    int excl = (int)(lsc[t] - ldeg[t]);
    int node = (b << 8) + t;
    if (node < N_NODES) {
        row_start[node] = segbase + excl;
        row_end[node]   = segbase + excl + (int)ldeg[t];
        atomicAdd(&ldh[min((int)ldeg[t], DBIN - 1)], 1u);   // LDS, not global
    }
    lcur[t] = excl;
    __syncthreads();
    // merge block histogram to global (<=128 aggregated atomics per block)
    if (t < DBIN && ldh[t]) atomicAdd(&dh[t], ldh[t]);
    for (int e = t; e < cntb; e += 256) {
        unsigned p = sbuf[e];
        int pos = atomicAdd(&lcur[p >> 17], 1);
        sdst[pos] = (int)(p & 0x1FFFFu);
    }
    __syncthreads();

    // per-wave bitonic sort of each row by src (len<=64; longer rows left as-is)
    const int wave = t >> 6, lane = t & 63;
    for (int n = wave; n < 256; n += 4) {
        int len = (int)ldeg[n];
        if (len < 2 || len > 64) continue;
        int lofs = (int)(lsc[n] - ldeg[n]);
        int v = (lane < len) ? sdst[lofs + lane] : 0x7FFFFFFF;
        #pragma unroll
        for (int k = 2; k <= 64; k <<= 1) {
            #pragma unroll
            for (int j = k >> 1; j > 0; j >>= 1) {
                int pv = __shfl_xor(v, j, 64);
                bool up    = (lane & k) == 0;
                bool lower = (lane & j) == 0;
                int mn = min(v, pv), mx = max(v, pv);
                v = (up == lower) ? mn : mx;
            }
        }
        if (lane < len) sdst[lofs + lane] = v;
    }
    __syncthreads();
    for (int e = t; e < cntb; e += 256)
        srtp[segbase + e] = (unsigned)sdst[e];
}

// ---------- degree-bin scan, descending, PARALLEL (was 1-thread serial: ~50us) ----------
__global__ __launch_bounds__(DBIN)
void degscan_kernel(const unsigned* __restrict__ dh, unsigned* __restrict__ dcur) {
    __shared__ unsigned s[DBIN];
    const int t = threadIdx.x;               // scan position over reversed bins
    unsigned v = dh[DBIN - 1 - t];
    s[t] = v;
    __syncthreads();
    for (int off = 1; off < DBIN; off <<= 1) {
        unsigned add = (t >= off) ? s[t - off] : 0u;
        __syncthreads();
        s[t] += add;
        __syncthreads();
    }
    dcur[DBIN - 1 - t] = s[t] - v;           // exclusive prefix in descending-degree order
}

// ---------- scatter nodes into degree-descending permutation (block-aggregated) ----------
__global__ __launch_bounds__(256)
void degscatter_kernel(const int* __restrict__ row_start, const int* __restrict__ row_end,
                       unsigned* __restrict__ dcur, int* __restrict__ perm) {
    __shared__ unsigned lh[DBIN];
    __shared__ unsigned lbase[DBIN];
    const int t = threadIdx.x;
    const int i = blockIdx.x * 256 + t;
    if (t < DBIN) lh[t] = 0u;
    __syncthreads();
    int d = -1; unsigned rank = 0;
    if (i < N_NODES) {
        d = min(row_end[i] - row_start[i], DBIN - 1);
        rank = atomicAdd(&lh[d], 1u);          // LDS rank within block's bin
    }
    __syncthreads();
    if (t < DBIN) {
        unsigned c = lh[t];
        lbase[t] = c ? atomicAdd(&dcur[t], c) : 0u;   // one global atomic per nonzero bin
    }
    __syncthreads();
    if (i < N_NODES) perm[lbase[d] + rank] = i;
}

// ---------- fused node linear: q = (x@Wq+bq)*scale (fp32); kv bf16 interleaved; sk fp32 ----------
// kv row layout (per node, 2*OUT bf16): [k0..3 v0..3 k4..7 v4..7 ...]
template <int IN, int OUT>
__global__ __launch_bounds__(256)
void lin_kernel(const float* __restrict__ x,
                const float* __restrict__ Wq, const float* __restrict__ bq,
                const float* __restrict__ Wk, const float* __restrict__ bk,
                const float* __restrict__ Wv, const float* __restrict__ bv,
                const float* __restrict__ Ws, const float* __restrict__ bs,
                float scale,
                float* __restrict__ q, unsigned short* __restrict__ kv,
                float* __restrict__ sk, int n)
{
    __shared__ float w[4 * IN * OUT];
    __shared__ float b[4 * OUT];
    for (int t = threadIdx.x; t < IN * OUT; t += blockDim.x) {
        w[t]            = Wq[t];
        w[IN*OUT + t]   = Wk[t];
        w[2*IN*OUT + t] = Wv[t];
        w[3*IN*OUT + t] = Ws[t];
    }
    for (int t = threadIdx.x; t < OUT; t += blockDim.x) {
        b[t]         = bq[t];
        b[OUT + t]   = bk[t];
        b[2*OUT + t] = bv[t];
        b[3*OUT + t] = bs[t];
    }
    __syncthreads();

    for (int i = blockIdx.x * blockDim.x + threadIdx.x; i < n;
         i += gridDim.x * blockDim.x) {
        float xi[IN];
        #pragma unroll
        for (int r = 0; r < IN; ++r) xi[r] = x[(size_t)i * IN + r];

        #pragma unroll
        for (int j = 0; j < OUT; ++j) {
            float aq = b[j], ak = b[OUT + j], av = b[2*OUT + j], as = b[3*OUT + j];
            #pragma unroll
            for (int r = 0; r < IN; ++r) {
                float xr = xi[r];
                aq += xr * w[r*OUT + j];
                ak += xr * w[IN*OUT + r*OUT + j];
                av += xr * w[2*IN*OUT + r*OUT + j];
                as += xr * w[3*IN*OUT + r*OUT + j];
            }
            int c = j >> 2, r4 = j & 3;
            q[(size_t)i * OUT + j]                  = aq * scale;
            kv[(size_t)i * 2 * OUT + c * 8 + r4]     = f2bf(ak);
            kv[(size_t)i * 2 * OUT + c * 8 + 4 + r4] = f2bf(av);
            sk[(size_t)i * OUT + j]                 = as;
        }
    }
}

// ---------- fused per-node attention: degree-permuted nodes, 1 load/edge/lane ----------
template <int D, bool POOL>
__global__ __launch_bounds__(256)
void fused_attn_kernel(const float* __restrict__ q, const unsigned short* __restrict__ kv,
                       const float* __restrict__ sk,
                       const int* __restrict__ row_start, const int* __restrict__ row_end,
                       const unsigned* __restrict__ sorted_src,
                       const int* __restrict__ perm,
                       const int* __restrict__ b32, const long long* __restrict__ b64,
                       const int* __restrict__ flag,
                       float* __restrict__ h, float* __restrict__ pool,
                       float* __restrict__ cnt)
{
    constexpr int L = D / 4;
    const int gpb = 256 / L;
    const int lj = threadIdx.x & (L - 1);
    int g = blockIdx.x * gpb + threadIdx.x / L;
    if (g >= N_NODES) return;
    const int i = perm[g];

    const float4 qj = *(const float4*)(q + (size_t)i * D + lj * 4);
    const int beg = row_start[i], end = row_end[i];

    float m = -INFINITY, denom = 0.f;
    float4 acc = make_float4(0.f, 0.f, 0.f, 0.f);

    if (beg < end) {
        const int last = end - 1;

        int s0 = (int)sorted_src[min(beg + 0, last)];
        int s1 = (int)sorted_src[min(beg + 1, last)];
        int s2 = (int)sorted_src[min(beg + 2, last)];
        int s3 = (int)sorted_src[min(beg + 3, last)];
        uint4 A0 = ((const uint4*)(kv + (size_t)s0 * (2 * D)))[lj];
        uint4 A1 = ((const uint4*)(kv + (size_t)s1 * (2 * D)))[lj];
        uint4 B0 = ((const uint4*)(kv + (size_t)s2 * (2 * D)))[lj];
        uint4 B1 = ((const uint4*)(kv + (size_t)s3 * (2 * D)))[lj];

        for (int e = beg; e < end; e += 4) {
            // ---- half 1: edges e, e+1 from A; refill A with e+4, e+5 ----
            {
                int sn0 = (int)sorted_src[min(e + 4, last)];
                int sn1 = (int)sorted_src[min(e + 5, last)];
                float k0,k1,k2,k3, l0,l1,l2,l3;
                unpack2(A0.x, k0, k1); unpack2(A0.y, k2, k3);
                unpack2(A1.x, l0, l1); unpack2(A1.y, l2, l3);
                float pa = k0*qj.x + k1*qj.y + k2*qj.z + k3*qj.w;
                float pb = l0*qj.x + l1*qj.y + l2*qj.z + l3*qj.w;
                #pragma unroll
                for (int off = L / 2; off; off >>= 1) {
                    pa += __shfl_xor(pa, off, L);
                    pb += __shfl_xor(pb, off, L);
                }
                if (e + 1 > last) pb = -INFINITY;
                float mn = fmaxf(m, fmaxf(pa, pb));
                float so = __expf(m - mn);
                float w0 = __expf(pa - mn);
                float w1 = __expf(pb - mn);
                float u0,u1,u2,u3, t0,t1,t2,t3;
                unpack2(A0.z, u0, u1); unpack2(A0.w, u2, u3);
                unpack2(A1.z, t0, t1); unpack2(A1.w, t2, t3);
                denom = denom * so + w0 + w1;
                acc.x = acc.x * so + w0 * u0 + w1 * t0;
                acc.y = acc.y * so + w0 * u1 + w1 * t1;
                acc.z = acc.z * so + w0 * u2 + w1 * t2;
                acc.w = acc.w * so + w0 * u3 + w1 * t3;
                m = mn;
                A0 = ((const uint4*)(kv + (size_t)sn0 * (2 * D)))[lj];
                A1 = ((const uint4*)(kv + (size_t)sn1 * (2 * D)))[lj];
            }
            // ---- half 2: edges e+2, e+3 from B; refill B with e+6, e+7 ----
            {
                int sn0 = (int)sorted_src[min(e + 6, last)];
                int sn1 = (int)sorted_src[min(e + 7, last)];
                float k0,k1,k2,k3, l0,l1,l2,l3;
                unpack2(B0.x, k0, k1); unpack2(B0.y, k2, k3);
                unpack2(B1.x, l0, l1); unpack2(B1.y, l2, l3);
                float pa = k0*qj.x + k1*qj.y + k2*qj.z + k3*qj.w;
                float pb = l0*qj.x + l1*qj.y + l2*qj.z + l3*qj.w;
                #pragma unroll
                for (int off = L / 2; off; off >>= 1) {
                    pa += __shfl_xor(pa, off, L);
                    pb += __shfl_xor(pb, off, L);
                }
                if (e + 2 > last) pa = -INFINITY;
                if (e + 3 > last) pb = -INFINITY;
                float mn = fmaxf(m, fmaxf(pa, pb));   // mn == m if both invalid
                float so = __expf(m - mn);
                float w0 = __expf(pa - mn);
                float w1 = __expf(pb - mn);
                float u0,u1,u2,u3, t0,t1,t2,t3;
                unpack2(B0.z, u0, u1); unpack2(B0.w, u2, u3);
                unpack2(B1.z, t0, t1); unpack2(B1.w, t2, t3);
                denom = denom * so + w0 + w1;
                acc.x = acc.x * so + w0 * u0 + w1 * t0;
                acc.y = acc.y * so + w0 * u1 + w1 * t1;
                acc.z = acc.z * so + w0 * u2 + w1 * t2;
                acc.w = acc.w * so + w0 * u3 + w1 * t3;
                m = mn;
                B0 = ((const uint4*)(kv + (size_t)sn0 * (2 * D)))[lj];
                B1 = ((const uint4*)(kv + (size_t)sn1 * (2 * D)))[lj];
            }
        }
    }

    float dn = 1.f / fmaxf(denom, 1e-16f);
    const float4 skv = *(const float4*)(sk + (size_t)i * D + lj * 4);
    float4 o;
    o.x = fmaxf(acc.x * dn + skv.x, 0.f);
    o.y = fmaxf(acc.y * dn + skv.y, 0.f);
    o.z = fmaxf(acc.z * dn + skv.z, 0.f);
    o.w = fmaxf(acc.w * dn + skv.w, 0.f);

    if (POOL) {
        int b = (*flag) ? (int)b64[i] : b32[i];
        float* pb = pool + b * 32 + lj * 4;
        atomicAdd(pb + 0, o.x);
        atomicAdd(pb + 1, o.y);
        atomicAdd(pb + 2, o.z);
        atomicAdd(pb + 3, o.w);
        if (lj == 0) atomicAdd(&cnt[b], 1.f);
    } else {
        *(float4*)(h + (size_t)i * D + lj * 4) = o;
    }
}

// ---------- final MLP: out = relu(mean @ Wf1 + bf1) @ Wf2 + bf2 ----------
__global__ __launch_bounds__(64)
void mlp_kernel(const float* __restrict__ pool, const float* __restrict__ cnt,
                const float* __restrict__ Wf1, const float* __restrict__ bf1,
                const float* __restrict__ Wf2, const float* __restrict__ bf2,
                float* __restrict__ out)
{
    int g = blockIdx.x;
    int h = threadIdx.x;            // 64 threads = 64 hidden units
    __shared__ float m[32];
    if (h < 32) {
        float c = fmaxf(cnt[g], 1.f);
        m[h] = pool[g * 32 + h] / c;
    }
    __syncthreads();
    float acc = bf1[h];
    #pragma unroll
    for (int r = 0; r < 32; ++r) acc += m[r] * Wf1[r * 64 + h];
    float hid = fmaxf(acc, 0.f);
    float c = hid * Wf2[h];
    #pragma unroll
    for (int off = 32; off; off >>= 1) c += __shfl_xor(c, off, 64);
    if (h == 0) out[g] = c + bf2[0];
}

extern "C" void kernel_launch(void* const* d_in, const int* in_sizes, int n_in,
                              void* d_out, int out_size, void* d_ws, size_t ws_size,
                              hipStream_t stream) {
    const float* x = (const float*)d_in[0];
    const void*  edge_index = d_in[1];
    const void*  batch      = d_in[2];
    const float* Wq1 = (const float*)d_in[3];  const float* bq1 = (const float*)d_in[4];
    const float* Wk1 = (const float*)d_in[5];  const float* bk1 = (const float*)d_in[6];
    const float* Wv1 = (const float*)d_in[7];  const float* bv1 = (const float*)d_in[8];
    const float* Ws1 = (const float*)d_in[9];  const float* bs1 = (const float*)d_in[10];
    const float* Wq2 = (const float*)d_in[11]; const float* bq2 = (const float*)d_in[12];
    const float* Wk2 = (const float*)d_in[13]; const float* bk2 = (const float*)d_in[14];
    const float* Wv2 = (const float*)d_in[15]; const float* bv2 = (const float*)d_in[16];
    const float* Ws2 = (const float*)d_in[17]; const float* bs2 = (const float*)d_in[18];
    const float* Wf1 = (const float*)d_in[19]; const float* bf1 = (const float*)d_in[20];
    const float* Wf2 = (const float*)d_in[21]; const float* bf2 = (const float*)d_in[22];
    float* out = (float*)d_out;

    // ---------------- workspace layout (~60 MB) ----------------
    char* ws = (char*)d_ws;
    size_t off = 0;
    auto carve = [&](size_t bytes) {
        char* p = ws + off;
        off = (off + bytes + 255) & ~(size_t)255;
        return p;
    };
    int*            flag     = (int*)            carve(16);
    int*            row_start= (int*)            carve((size_t)N_NODES * 4);
    int*            row_end  = (int*)            carve((size_t)N_NODES * 4);
    unsigned*       bcur     = (unsigned*)       carve((size_t)NBKT * 4);
    float*          pool     = (float*)          carve((size_t)N_GRAPHS * 32 * 4);
    float*          cnt      = (float*)          carve((size_t)N_GRAPHS * 4);
    unsigned*       dh       = (unsigned*)       carve((size_t)DBIN * 4);
    unsigned*       dcur     = (unsigned*)       carve((size_t)DBIN * 4);
    int*            perm     = (int*)            carve((size_t)N_NODES * 4);
    unsigned*       srtp     = (unsigned*)       carve((size_t)NBKT * BCAP * 4);  // padded pairs -> sorted srcs
    float*          qb       = (float*)          carve((size_t)N_NODES * 32 * 4);
    unsigned short* kvb      = (unsigned short*) carve((size_t)N_NODES * 64 * 2);
    float*          skb      = (float*)          carve((size_t)N_NODES * 32 * 4);
    float*          h1       = (float*)          carve((size_t)N_NODES * 16 * 4);
    (void)ws_size; (void)in_sizes; (void)n_in; (void)out_size;

    const int* ei32 = (const int*)edge_index;
    const long long* ei64 = (const long long*)edge_index;
    const int* b32 = (const int*)batch;
    const long long* b64 = (const long long*)batch;

    const dim3 blk(256);

    // ---- CSR build: padded buckets, single partition pass, fused build+rowsort ----
    detect_kernel<<<1, 64, 0, stream>>>(ei64, flag);
    init_kernel<<<(N_GRAPHS * 32 + 255) / 256, blk, 0, stream>>>(bcur, pool, cnt, dh);
    partition_kernel<<<(N_EDGES + PCHUNK - 1) / PCHUNK, blk, 0, stream>>>(
        ei32, ei64, flag, bcur, srtp);
    build_kernel<<<NBKT, blk, 0, stream>>>(srtp, bcur, row_start, row_end, dh);
    degscan_kernel<<<1, DBIN, 0, stream>>>(dh, dcur);
    degscatter_kernel<<<(N_NODES + 255) / 256, blk, 0, stream>>>(
        row_start, row_end, dcur, perm);

    // ---- layer 1 (11 -> 16): L=4 lanes/node, 64 nodes/block ----
    lin_kernel<11, 16><<<(N_NODES + 255) / 256, blk, 0, stream>>>(
        x, Wq1, bq1, Wk1, bk1, Wv1, bv1, Ws1, bs1, 0.25f,
        qb, kvb, skb, N_NODES);
    fused_attn_kernel<16, false><<<(N_NODES + 63) / 64, blk, 0, stream>>>(
        qb, kvb, skb, row_start, row_end, srtp, perm, b32, b64, flag, h1, pool, cnt);

    // ---- layer 2 (16 -> 32): L=8 lanes/node, 32 nodes/block; pooling fused ----
    lin_kernel<16, 32><<<(N_NODES + 255) / 256, blk, 0, stream>>>(
        h1, Wq2, bq2, Wk2, bk2, Wv2, bv2, Ws2, bs2, 0.17677669529663688f,
        qb, kvb, skb, N_NODES);
    fused_attn_kernel<32, true><<<(N_NODES + 31) / 32, blk, 0, stream>>>(
        qb, kvb, skb, row_start, row_end, srtp, perm, b32, b64, flag, nullptr, pool, cnt);

    // ---- MLP head ----
    mlp_kernel<<<N_GRAPHS, 64, 0, stream>>>(pool, cnt, Wf1, bf1, Wf2, bf2, out);
}

// Round 14
// 347.887 us; speedup vs baseline: 1.9516x; 1.0093x over previous
//
#include <hip/hip_runtime.h>
#include <hip/hip_bf16.h>
#include <math.h>

#define N_NODES  100000
#define N_EDGES  3200000
#define N_GRAPHS 1000
#define NBKT ((N_NODES + 255) >> 8)       // 391 buckets of 256 nodes
#define BCAP 9216                         // padded bucket capacity (mean 8192, 11 sigma)
#define PCHUNK 4096
#define EPT (PCHUNK / 256)                // 16 edges per thread
#define DBIN 128                          // degree bins for node permutation

// ---------- fp32 <-> bf16 helpers ----------
__device__ __forceinline__ unsigned short f2bf(float f) {
    unsigned u = __float_as_uint(f);
    return (unsigned short)((u + 0x7FFFu + ((u >> 16) & 1u)) >> 16);   // RNE
}
// unpack a uint holding two bf16 (lo, hi) into two floats
__device__ __forceinline__ void unpack2(unsigned u, float& a, float& b) {
    a = __uint_as_float(u << 16);
    b = __uint_as_float(u & 0xFFFF0000u);
}

// ---------- detect whether integer inputs are int64 or int32 ----------
__global__ void detect_kernel(const long long* __restrict__ idx, int* __restrict__ flag) {
    int t = threadIdx.x;
    unsigned long long hi = ((unsigned long long)idx[t]) >> 32;
    unsigned long long any = __ballot(hi != 0ull);
    if (t == 0) *flag = (any == 0ull) ? 1 : 0;   // 1 => int64, 0 => int32
}

// ---------- init bucket cursors / pool / cnt ----------
__global__ __launch_bounds__(256)
void init_kernel(unsigned* __restrict__ bcur, float* __restrict__ pool,
                 float* __restrict__ cnt) {
    int t = blockIdx.x * blockDim.x + threadIdx.x;
    if (t < NBKT)         bcur[t] = (unsigned)t * BCAP;
    if (t < N_GRAPHS*32)  pool[t] = 0.f;
    if (t < N_GRAPHS)     cnt[t]  = 0.f;
}

// ---------- partition edges into padded bucket segments (LDS counting sort) ----------
// packed pair: (dst & 255) << 17 | src    (src < 2^17)
__global__ __launch_bounds__(256)
void partition_kernel(const int* __restrict__ idx32, const long long* __restrict__ idx64,
                      const int* __restrict__ flag,
                      unsigned* __restrict__ bcur, unsigned* __restrict__ srtp) {
    __shared__ unsigned       sbuf[PCHUNK];   // 16 KB packed pairs, chunk-sorted
    __shared__ unsigned short sbkt[PCHUNK];   // 8 KB bucket per slot
    __shared__ unsigned lhist[NBKT];
    __shared__ unsigned lscan[512];
    __shared__ unsigned gbase[NBKT];
    const int is64 = *flag;
    const int t = threadIdx.x;
    const int base = blockIdx.x * PCHUNK;
    const int nval = min(PCHUNK, N_EDGES - base);

    for (int b = t; b < NBKT; b += 256) lhist[b] = 0u;
    __syncthreads();

    unsigned pr[EPT]; unsigned short br[EPT]; unsigned short rr[EPT];
    #pragma unroll
    for (int r = 0; r < EPT; ++r) {
        int e = base + r * 256 + t;
        br[r] = 0xFFFF;
        if (e < N_EDGES) {
            int s = is64 ? (int)idx64[e]           : idx32[e];
            int d = is64 ? (int)idx64[N_EDGES + e] : idx32[N_EDGES + e];
            unsigned bk = ((unsigned)d) >> 8;
            pr[r] = (((unsigned)d & 255u) << 17) | (unsigned)s;
            br[r] = (unsigned short)bk;
            rr[r] = (unsigned short)atomicAdd(&lhist[bk], 1u);
        }
    }
    __syncthreads();

    // inclusive scan of lhist over 512 padded slots
    lscan[t]       = (t < NBKT)       ? lhist[t]       : 0u;
    lscan[t + 256] = (t + 256 < NBKT) ? lhist[t + 256] : 0u;
    __syncthreads();
    for (int off = 1; off < 512; off <<= 1) {
        unsigned v0 = (t >= off)       ? lscan[t - off]       : 0u;
        unsigned v1 = (t + 256 >= off) ? lscan[t + 256 - off] : 0u;
        __syncthreads();
        lscan[t] += v0; lscan[t + 256] += v1;
        __syncthreads();
    }

    // reserve global space per bucket (absolute position in padded layout)
    for (int b = t; b < NBKT; b += 256) {
        unsigned c = lhist[b];
        if (c) gbase[b] = atomicAdd(&bcur[b], c);
    }

    // place into chunk-sorted LDS order
    #pragma unroll
    for (int r = 0; r < EPT; ++r) {
        if (br[r] != 0xFFFF) {
            unsigned b = br[r];
            unsigned slot = lscan[b] - lhist[b] + rr[r];
            sbuf[slot] = pr[r];
            sbkt[slot] = (unsigned short)b;
        }
    }
    __syncthreads();

    // coalesced write-out per bucket run
    for (int slot = t; slot < nval; slot += 256) {
        unsigned p = sbuf[slot];
        unsigned b = sbkt[slot];
        unsigned lst = lscan[b] - lhist[b];
        srtp[gbase[b] + ((unsigned)slot - lst)] = p;
    }
}

// ---------- fused CSR build + per-row src sort + per-block degree histogram ----------
__global__ __launch_bounds__(256)
void build_kernel(unsigned* __restrict__ srtp, const unsigned* __restrict__ bcur,
                  int* __restrict__ row_start, int* __restrict__ row_end,
                  unsigned* __restrict__ dhb) {
    __shared__ unsigned sbuf[BCAP];      // 36 KB raw pairs
    __shared__ int      sdst[BCAP];      // 36 KB row-grouped srcs
    __shared__ unsigned ldeg[256];
    __shared__ unsigned lsc[256];
    __shared__ int      lcur[256];
    __shared__ unsigned ldh[DBIN];       // block-local degree histogram
    const int b = blockIdx.x;
    const int t = threadIdx.x;
    const int segbase = b * BCAP;
    const int cntb = min((int)bcur[b] - segbase, BCAP);

    ldeg[t] = 0u;
    if (t < DBIN) ldh[t] = 0u;
    __syncthreads();
    for (int e = t; e < cntb; e += 256) {
        unsigned p = srtp[segbase + e];
        sbuf[e] = p;
        atomicAdd(&ldeg[p >> 17], 1u);
    }
    __syncthreads();
    lsc[t] = ldeg[t];
    __syncthreads();
    for (int off = 1; off < 256; off <<= 1) {
        unsigned v = (t >= off) ? lsc[t - off] : 0u;
        __syncthreads();
        lsc[t] += v;
        __syncthreads();
    }
    int excl = (int)(lsc[t] - ldeg[t]);
    int node = (b << 8) + t;
    if (node < N_NODES) {
        row_start[node] = segbase + excl;
        row_end[node]   = segbase + excl + (int)ldeg[t];
        atomicAdd(&ldh[min((int)ldeg[t], DBIN - 1)], 1u);   // LDS only
    }
    lcur[t] = excl;
    __syncthreads();
    // plain store of block histogram -- NO global atomics
    if (t < DBIN) dhb[(size_t)b * DBIN + t] = ldh[t];
    for (int e = t; e < cntb; e += 256) {
        unsigned p = sbuf[e];
        int pos = atomicAdd(&lcur[p >> 17], 1);
        sdst[pos] = (int)(p & 0x1FFFFu);
    }
    __syncthreads();

    // per-wave bitonic sort of each row by src (len<=64; longer rows left as-is)
    const int wave = t >> 6, lane = t & 63;
    for (int n = wave; n < 256; n += 4) {
        int len = (int)ldeg[n];
        if (len < 2 || len > 64) continue;
        int lofs = (int)(lsc[n] - ldeg[n]);
        int v = (lane < len) ? sdst[lofs + lane] : 0x7FFFFFFF;
        #pragma unroll
        for (int k = 2; k <= 64; k <<= 1) {
            #pragma unroll
            for (int j = k >> 1; j > 0; j >>= 1) {
                int pv = __shfl_xor(v, j, 64);
                bool up    = (lane & k) == 0;
                bool lower = (lane & j) == 0;
                int mn = min(v, pv), mx = max(v, pv);
                v = (up == lower) ? mn : mx;
            }
        }
        if (lane < len) sdst[lofs + lane] = v;
    }
    __syncthreads();
    for (int e = t; e < cntb; e += 256)
        srtp[segbase + e] = (unsigned)sdst[e];
}

// ---------- per-bin exclusive prefix over blocks (atomic-free counting sort, pass 2) ----------
// one block per degree bin; scans dhb[blk][bin] over blk, leaves exclusive prefix in place,
// writes bin total to dh[bin].
__global__ __launch_bounds__(512)
void pscan_kernel(unsigned* __restrict__ dhb, unsigned* __restrict__ dh) {
    __shared__ unsigned s[512];
    const int bin = blockIdx.x;
    const int t = threadIdx.x;
    unsigned v = (t < NBKT) ? dhb[(size_t)t * DBIN + bin] : 0u;
    s[t] = v;
    __syncthreads();
    for (int off = 1; off < 512; off <<= 1) {
        unsigned add = (t >= off) ? s[t - off] : 0u;
        __syncthreads();
        s[t] += add;
        __syncthreads();
    }
    if (t < NBKT) dhb[(size_t)t * DBIN + bin] = s[t] - v;   // exclusive prefix
    if (t == 511) dh[bin] = s[511];                          // bin total
}

// ---------- degree-bin base scan (descending degree) ----------
__global__ __launch_bounds__(DBIN)
void degscan_kernel(const unsigned* __restrict__ dh, unsigned* __restrict__ dcur) {
    __shared__ unsigned s[DBIN];
    const int t = threadIdx.x;               // scan position over reversed bins
    unsigned v = dh[DBIN - 1 - t];
    s[t] = v;
    __syncthreads();
    for (int off = 1; off < DBIN; off <<= 1) {
        unsigned add = (t >= off) ? s[t - off] : 0u;
        __syncthreads();
        s[t] += add;
        __syncthreads();
    }
    dcur[DBIN - 1 - t] = s[t] - v;           // exclusive prefix, descending-degree order
}

// ---------- scatter nodes into degree-descending permutation (NO global atomics) ----------
__global__ __launch_bounds__(256)
void degscatter_kernel(const int* __restrict__ row_start, const int* __restrict__ row_end,
                       const unsigned* __restrict__ dcur, const unsigned* __restrict__ dhb,
                       int* __restrict__ perm) {
    __shared__ unsigned lh[DBIN];
    const int t = threadIdx.x;
    const int blk = blockIdx.x;
    const int i = blk * 256 + t;
    if (t < DBIN) lh[t] = 0u;
    __syncthreads();
    if (i < N_NODES) {
        int d = min(row_end[i] - row_start[i], DBIN - 1);
        unsigned rank = atomicAdd(&lh[d], 1u);           // LDS rank within block's bin
        perm[dcur[d] + dhb[(size_t)blk * DBIN + d] + rank] = i;
    }
}

// ---------- fused node linear: q = (x@Wq+bq)*scale (fp32); kv bf16 interleaved; sk fp32 ----------
// kv row layout (per node, 2*OUT bf16): [k0..3 v0..3 k4..7 v4..7 ...]
template <int IN, int OUT>
__global__ __launch_bounds__(256)
void lin_kernel(const float* __restrict__ x,
                const float* __restrict__ Wq, const float* __restrict__ bq,
                const float* __restrict__ Wk, const float* __restrict__ bk,
                const float* __restrict__ Wv, const float* __restrict__ bv,
                const float* __restrict__ Ws, const float* __restrict__ bs,
                float scale,
                float* __restrict__ q, unsigned short* __restrict__ kv,
                float* __restrict__ sk, int n)
{
    __shared__ float w[4 * IN * OUT];
    __shared__ float b[4 * OUT];
    for (int t = threadIdx.x; t < IN * OUT; t += blockDim.x) {
        w[t]            = Wq[t];
        w[IN*OUT + t]   = Wk[t];
        w[2*IN*OUT + t] = Wv[t];
        w[3*IN*OUT + t] = Ws[t];
    }
    for (int t = threadIdx.x; t < OUT; t += blockDim.x) {
        b[t]         = bq[t];
        b[OUT + t]   = bk[t];
        b[2*OUT + t] = bv[t];
        b[3*OUT + t] = bs[t];
    }
    __syncthreads();

    for (int i = blockIdx.x * blockDim.x + threadIdx.x; i < n;
         i += gridDim.x * blockDim.x) {
        float xi[IN];
        #pragma unroll
        for (int r = 0; r < IN; ++r) xi[r] = x[(size_t)i * IN + r];

        #pragma unroll
        for (int j = 0; j < OUT; ++j) {
            float aq = b[j], ak = b[OUT + j], av = b[2*OUT + j], as = b[3*OUT + j];
            #pragma unroll
            for (int r = 0; r < IN; ++r) {
                float xr = xi[r];
                aq += xr * w[r*OUT + j];
                ak += xr * w[IN*OUT + r*OUT + j];
                av += xr * w[2*IN*OUT + r*OUT + j];
                as += xr * w[3*IN*OUT + r*OUT + j];
            }
            int c = j >> 2, r4 = j & 3;
            q[(size_t)i * OUT + j]                  = aq * scale;
            kv[(size_t)i * 2 * OUT + c * 8 + r4]     = f2bf(ak);
            kv[(size_t)i * 2 * OUT + c * 8 + 4 + r4] = f2bf(av);
            sk[(size_t)i * OUT + j]                 = as;
        }
    }
}

// ---------- fused per-node attention: degree-permuted nodes, 1 load/edge/lane ----------
template <int D, bool POOL>
__global__ __launch_bounds__(256)
void fused_attn_kernel(const float* __restrict__ q, const unsigned short* __restrict__ kv,
                       const float* __restrict__ sk,
                       const int* __restrict__ row_start, const int* __restrict__ row_end,
                       const unsigned* __restrict__ sorted_src,
                       const int* __restrict__ perm,
                       const int* __restrict__ b32, const long long* __restrict__ b64,
                       const int* __restrict__ flag,
                       float* __restrict__ h, float* __restrict__ pool,
                       float* __restrict__ cnt)
{
    constexpr int L = D / 4;
    const int gpb = 256 / L;
    const int lj = threadIdx.x & (L - 1);
    int g = blockIdx.x * gpb + threadIdx.x / L;
    if (g >= N_NODES) return;
    const int i = perm[g];

    const float4 qj = *(const float4*)(q + (size_t)i * D + lj * 4);
    const int beg = row_start[i], end = row_end[i];

    float m = -INFINITY, denom = 0.f;
    float4 acc = make_float4(0.f, 0.f, 0.f, 0.f);

    if (beg < end) {
        const int last = end - 1;

        int s0 = (int)sorted_src[min(beg + 0, last)];
        int s1 = (int)sorted_src[min(beg + 1, last)];
        int s2 = (int)sorted_src[min(beg + 2, last)];
        int s3 = (int)sorted_src[min(beg + 3, last)];
        uint4 A0 = ((const uint4*)(kv + (size_t)s0 * (2 * D)))[lj];
        uint4 A1 = ((const uint4*)(kv + (size_t)s1 * (2 * D)))[lj];
        uint4 B0 = ((const uint4*)(kv + (size_t)s2 * (2 * D)))[lj];
        uint4 B1 = ((const uint4*)(kv + (size_t)s3 * (2 * D)))[lj];

        for (int e = beg; e < end; e += 4) {
            // ---- half 1: edges e, e+1 from A; refill A with e+4, e+5 ----
            {
                int sn0 = (int)sorted_src[min(e + 4, last)];
                int sn1 = (int)sorted_src[min(e + 5, last)];
                float k0,k1,k2,k3, l0,l1,l2,l3;
                unpack2(A0.x, k0, k1); unpack2(A0.y, k2, k3);
                unpack2(A1.x, l0, l1); unpack2(A1.y, l2, l3);
                float pa = k0*qj.x + k1*qj.y + k2*qj.z + k3*qj.w;
                float pb = l0*qj.x + l1*qj.y + l2*qj.z + l3*qj.w;
                #pragma unroll
                for (int off = L / 2; off; off >>= 1) {
                    pa += __shfl_xor(pa, off, L);
                    pb += __shfl_xor(pb, off, L);
                }
                if (e + 1 > last) pb = -INFINITY;
                float mn = fmaxf(m, fmaxf(pa, pb));
                float so = __expf(m - mn);
                float w0 = __expf(pa - mn);
                float w1 = __expf(pb - mn);
                float u0,u1,u2,u3, t0,t1,t2,t3;
                unpack2(A0.z, u0, u1); unpack2(A0.w, u2, u3);
                unpack2(A1.z, t0, t1); unpack2(A1.w, t2, t3);
                denom = denom * so + w0 + w1;
                acc.x = acc.x * so + w0 * u0 + w1 * t0;
                acc.y = acc.y * so + w0 * u1 + w1 * t1;
                acc.z = acc.z * so + w0 * u2 + w1 * t2;
                acc.w = acc.w * so + w0 * u3 + w1 * t3;
                m = mn;
                A0 = ((const uint4*)(kv + (size_t)sn0 * (2 * D)))[lj];
                A1 = ((const uint4*)(kv + (size_t)sn1 * (2 * D)))[lj];
            }
            // ---- half 2: edges e+2, e+3 from B; refill B with e+6, e+7 ----
            {
                int sn0 = (int)sorted_src[min(e + 6, last)];
                int sn1 = (int)sorted_src[min(e + 7, last)];
                float k0,k1,k2,k3, l0,l1,l2,l3;
                unpack2(B0.x, k0, k1); unpack2(B0.y, k2, k3);
                unpack2(B1.x, l0, l1); unpack2(B1.y, l2, l3);
                float pa = k0*qj.x + k1*qj.y + k2*qj.z + k3*qj.w;
                float pb = l0*qj.x + l1*qj.y + l2*qj.z + l3*qj.w;
                #pragma unroll
                for (int off = L / 2; off; off >>= 1) {
                    pa += __shfl_xor(pa, off, L);
                    pb += __shfl_xor(pb, off, L);
                }
                if (e + 2 > last) pa = -INFINITY;
                if (e + 3 > last) pb = -INFINITY;
                float mn = fmaxf(m, fmaxf(pa, pb));   // mn == m if both invalid
                float so = __expf(m - mn);
                float w0 = __expf(pa - mn);
                float w1 = __expf(pb - mn);
                float u0,u1,u2,u3, t0,t1,t2,t3;
                unpack2(B0.z, u0, u1); unpack2(B0.w, u2, u3);
                unpack2(B1.z, t0, t1); unpack2(B1.w, t2, t3);
                denom = denom * so + w0 + w1;
                acc.x = acc.x * so + w0 * u0 + w1 * t0;
                acc.y = acc.y * so + w0 * u1 + w1 * t1;
                acc.z = acc.z * so + w0 * u2 + w1 * t2;
                acc.w = acc.w * so + w0 * u3 + w1 * t3;
                m = mn;
                B0 = ((const uint4*)(kv + (size_t)sn0 * (2 * D)))[lj];
                B1 = ((const uint4*)(kv + (size_t)sn1 * (2 * D)))[lj];
            }
        }
    }

    float dn = 1.f / fmaxf(denom, 1e-16f);
    const float4 skv = *(const float4*)(sk + (size_t)i * D + lj * 4);
    float4 o;
    o.x = fmaxf(acc.x * dn + skv.x, 0.f);
    o.y = fmaxf(acc.y * dn + skv.y, 0.f);
    o.z = fmaxf(acc.z * dn + skv.z, 0.f);
    o.w = fmaxf(acc.w * dn + skv.w, 0.f);

    if (POOL) {
        int b = (*flag) ? (int)b64[i] : b32[i];
        float* pb = pool + b * 32 + lj * 4;
        atomicAdd(pb + 0, o.x);
        atomicAdd(pb + 1, o.y);
        atomicAdd(pb + 2, o.z);
        atomicAdd(pb + 3, o.w);
        if (lj == 0) atomicAdd(&cnt[b], 1.f);
    } else {
        *(float4*)(h + (size_t)i * D + lj * 4) = o;
    }
}

// ---------- final MLP: out = relu(mean @ Wf1 + bf1) @ Wf2 + bf2 ----------
__global__ __launch_bounds__(64)
void mlp_kernel(const float* __restrict__ pool, const float* __restrict__ cnt,
                const float* __restrict__ Wf1, const float* __restrict__ bf1,
                const float* __restrict__ Wf2, const float* __restrict__ bf2,
                float* __restrict__ out)
{
    int g = blockIdx.x;
    int h = threadIdx.x;            // 64 threads = 64 hidden units
    __shared__ float m[32];
    if (h < 32) {
        float c = fmaxf(cnt[g], 1.f);
        m[h] = pool[g * 32 + h] / c;
    }
    __syncthreads();
    float acc = bf1[h];
    #pragma unroll
    for (int r = 0; r < 32; ++r) acc += m[r] * Wf1[r * 64 + h];
    float hid = fmaxf(acc, 0.f);
    float c = hid * Wf2[h];
    #pragma unroll
    for (int off = 32; off; off >>= 1) c += __shfl_xor(c, off, 64);
    if (h == 0) out[g] = c + bf2[0];
}

extern "C" void kernel_launch(void* const* d_in, const int* in_sizes, int n_in,
                              void* d_out, int out_size, void* d_ws, size_t ws_size,
                              hipStream_t stream) {
    const float* x = (const float*)d_in[0];
    const void*  edge_index = d_in[1];
    const void*  batch      = d_in[2];
    const float* Wq1 = (const float*)d_in[3];  const float* bq1 = (const float*)d_in[4];
    const float* Wk1 = (const float*)d_in[5];  const float* bk1 = (const float*)d_in[6];
    const float* Wv1 = (const float*)d_in[7];  const float* bv1 = (const float*)d_in[8];
    const float* Ws1 = (const float*)d_in[9];  const float* bs1 = (const float*)d_in[10];
    const float* Wq2 = (const float*)d_in[11]; const float* bq2 = (const float*)d_in[12];
    const float* Wk2 = (const float*)d_in[13]; const float* bk2 = (const float*)d_in[14];
    const float* Wv2 = (const float*)d_in[15]; const float* bv2 = (const float*)d_in[16];
    const float* Ws2 = (const float*)d_in[17]; const float* bs2 = (const float*)d_in[18];
    const float* Wf1 = (const float*)d_in[19]; const float* bf1 = (const float*)d_in[20];
    const float* Wf2 = (const float*)d_in[21]; const float* bf2 = (const float*)d_in[22];
    float* out = (float*)d_out;

    // ---------------- workspace layout (~60 MB) ----------------
    char* ws = (char*)d_ws;
    size_t off = 0;
    auto carve = [&](size_t bytes) {
        char* p = ws + off;
        off = (off + bytes + 255) & ~(size_t)255;
        return p;
    };
    int*            flag     = (int*)            carve(16);
    int*            row_start= (int*)            carve((size_t)N_NODES * 4);
    int*            row_end  = (int*)            carve((size_t)N_NODES * 4);
    unsigned*       bcur     = (unsigned*)       carve((size_t)NBKT * 4);
    float*          pool     = (float*)          carve((size_t)N_GRAPHS * 32 * 4);
    float*          cnt      = (float*)          carve((size_t)N_GRAPHS * 4);
    unsigned*       dh       = (unsigned*)       carve((size_t)DBIN * 4);
    unsigned*       dcur     = (unsigned*)       carve((size_t)DBIN * 4);
    unsigned*       dhb      = (unsigned*)       carve((size_t)NBKT * DBIN * 4);
    int*            perm     = (int*)            carve((size_t)N_NODES * 4);
    unsigned*       srtp     = (unsigned*)       carve((size_t)NBKT * BCAP * 4);  // padded pairs -> sorted srcs
    float*          qb       = (float*)          carve((size_t)N_NODES * 32 * 4);
    unsigned short* kvb      = (unsigned short*) carve((size_t)N_NODES * 64 * 2);
    float*          skb      = (float*)          carve((size_t)N_NODES * 32 * 4);
    float*          h1       = (float*)          carve((size_t)N_NODES * 16 * 4);
    (void)ws_size; (void)in_sizes; (void)n_in; (void)out_size;

    const int* ei32 = (const int*)edge_index;
    const long long* ei64 = (const long long*)edge_index;
    const int* b32 = (const int*)batch;
    const long long* b64 = (const long long*)batch;

    const dim3 blk(256);

    // ---- CSR build: padded buckets, single partition pass, fused build+rowsort ----
    detect_kernel<<<1, 64, 0, stream>>>(ei64, flag);
    init_kernel<<<(N_GRAPHS * 32 + 255) / 256, blk, 0, stream>>>(bcur, pool, cnt);
    partition_kernel<<<(N_EDGES + PCHUNK - 1) / PCHUNK, blk, 0, stream>>>(
        ei32, ei64, flag, bcur, srtp);
    build_kernel<<<NBKT, blk, 0, stream>>>(srtp, bcur, row_start, row_end, dhb);
    pscan_kernel<<<DBIN, 512, 0, stream>>>(dhb, dh);
    degscan_kernel<<<1, DBIN, 0, stream>>>(dh, dcur);
    degscatter_kernel<<<NBKT, blk, 0, stream>>>(row_start, row_end, dcur, dhb, perm);

    // ---- layer 1 (11 -> 16): L=4 lanes/node, 64 nodes/block ----
    lin_kernel<11, 16><<<(N_NODES + 255) / 256, blk, 0, stream>>>(
        x, Wq1, bq1, Wk1, bk1, Wv1, bv1, Ws1, bs1, 0.25f,
        qb, kvb, skb, N_NODES);
    fused_attn_kernel<16, false><<<(N_NODES + 63) / 64, blk, 0, stream>>>(
        qb, kvb, skb, row_start, row_end, srtp, perm, b32, b64, flag, h1, pool, cnt);

    // ---- layer 2 (16 -> 32): L=8 lanes/node, 32 nodes/block; pooling fused ----
    lin_kernel<16, 32><<<(N_NODES + 255) / 256, blk, 0, stream>>>(
        h1, Wq2, bq2, Wk2, bk2, Wv2, bv2, Ws2, bs2, 0.17677669529663688f,
        qb, kvb, skb, N_NODES);
    fused_attn_kernel<32, true><<<(N_NODES + 31) / 32, blk, 0, stream>>>(
        qb, kvb, skb, row_start, row_end, srtp, perm, b32, b64, flag, nullptr, pool, cnt);

    // ---- MLP head ----
    mlp_kernel<<<N_GRAPHS, 64, 0, stream>>>(pool, cnt, Wf1, bf1, Wf2, bf2, out);
}

// Round 15
// 343.697 us; speedup vs baseline: 1.9754x; 1.0122x over previous
//
#include <hip/hip_runtime.h>
#include <hip/hip_bf16.h>
#include <math.h>

#define N_NODES  100000
#define N_EDGES  3200000
#define N_GRAPHS 1000
#define NBKT ((N_NODES + 255) >> 8)       // 391 buckets of 256 nodes
#define BCAP 9216                         // padded bucket capacity (mean 8192, 11 sigma)
#define PCHUNK 4096
#define EPT (PCHUNK / 256)                // 16 edges per thread
#define DBIN 128                          // degree bins for node permutation

// ---------- fp32 <-> bf16 helpers ----------
__device__ __forceinline__ unsigned short f2bf(float f) {
    unsigned u = __float_as_uint(f);
    return (unsigned short)((u + 0x7FFFu + ((u >> 16) & 1u)) >> 16);   // RNE
}
// unpack a uint holding two bf16 (lo, hi) into two floats
__device__ __forceinline__ void unpack2(unsigned u, float& a, float& b) {
    a = __uint_as_float(u << 16);
    b = __uint_as_float(u & 0xFFFF0000u);
}

// ---------- init bucket cursors / pool / cnt + fused int64/int32 detect ----------
__global__ __launch_bounds__(256)
void init_kernel(const long long* __restrict__ idx, int* __restrict__ flag,
                 unsigned* __restrict__ bcur, float* __restrict__ pool,
                 float* __restrict__ cnt) {
    int t = blockIdx.x * blockDim.x + threadIdx.x;
    if (blockIdx.x == 0 && threadIdx.x < 64) {
        unsigned long long hi = ((unsigned long long)idx[threadIdx.x]) >> 32;
        unsigned long long any = __ballot(hi != 0ull);
        if (threadIdx.x == 0) *flag = (any == 0ull) ? 1 : 0;   // 1 => int64
    }
    if (t < NBKT)         bcur[t] = (unsigned)t * BCAP;
    if (t < N_GRAPHS*32)  pool[t] = 0.f;
    if (t < N_GRAPHS)     cnt[t]  = 0.f;
}

// ---------- partition edges into padded bucket segments (LDS counting sort) ----------
// packed pair: (dst & 255) << 17 | src    (src < 2^17); paired vector edge loads.
__global__ __launch_bounds__(256)
void partition_kernel(const int* __restrict__ idx32, const long long* __restrict__ idx64,
                      const int* __restrict__ flag,
                      unsigned* __restrict__ bcur, unsigned* __restrict__ srtp) {
    __shared__ unsigned       sbuf[PCHUNK];   // 16 KB packed pairs, chunk-sorted
    __shared__ unsigned short sbkt[PCHUNK];   // 8 KB bucket per slot
    __shared__ unsigned lhist[NBKT];
    __shared__ unsigned lscan[512];
    __shared__ unsigned gbase[NBKT];
    const int is64 = *flag;
    const int t = threadIdx.x;
    const int base = blockIdx.x * PCHUNK;
    const int nval = min(PCHUNK, N_EDGES - base);

    for (int b = t; b < NBKT; b += 256) lhist[b] = 0u;
    __syncthreads();

    unsigned pr[EPT]; unsigned short br[EPT]; unsigned short rr[EPT];
    #pragma unroll
    for (int r = 0; r < EPT / 2; ++r) {
        int e0 = base + r * 512 + 2 * t;      // pairs: edges e0, e0+1
        br[2*r] = 0xFFFF; br[2*r+1] = 0xFFFF;
        if (e0 < N_EDGES) {                   // N_EDGES even -> e0+1 also valid
            int s0, s1, d0, d1;
            if (is64) {
                longlong2 sp = *(const longlong2*)(idx64 + e0);
                longlong2 dp = *(const longlong2*)(idx64 + N_EDGES + e0);
                s0 = (int)sp.x; s1 = (int)sp.y; d0 = (int)dp.x; d1 = (int)dp.y;
            } else {
                int2 sp = *(const int2*)(idx32 + e0);
                int2 dp = *(const int2*)(idx32 + N_EDGES + e0);
                s0 = sp.x; s1 = sp.y; d0 = dp.x; d1 = dp.y;
            }
            unsigned bk0 = ((unsigned)d0) >> 8, bk1 = ((unsigned)d1) >> 8;
            pr[2*r]   = (((unsigned)d0 & 255u) << 17) | (unsigned)s0;
            pr[2*r+1] = (((unsigned)d1 & 255u) << 17) | (unsigned)s1;
            br[2*r]   = (unsigned short)bk0;
            br[2*r+1] = (unsigned short)bk1;
            rr[2*r]   = (unsigned short)atomicAdd(&lhist[bk0], 1u);
            rr[2*r+1] = (unsigned short)atomicAdd(&lhist[bk1], 1u);
        }
    }
    __syncthreads();

    // inclusive scan of lhist over 512 padded slots
    lscan[t]       = (t < NBKT)       ? lhist[t]       : 0u;
    lscan[t + 256] = (t + 256 < NBKT) ? lhist[t + 256] : 0u;
    __syncthreads();
    for (int off = 1; off < 512; off <<= 1) {
        unsigned v0 = (t >= off)       ? lscan[t - off]       : 0u;
        unsigned v1 = (t + 256 >= off) ? lscan[t + 256 - off] : 0u;
        __syncthreads();
        lscan[t] += v0; lscan[t + 256] += v1;
        __syncthreads();
    }

    // reserve global space per bucket (absolute position in padded layout)
    for (int b = t; b < NBKT; b += 256) {
        unsigned c = lhist[b];
        if (c) gbase[b] = atomicAdd(&bcur[b], c);
    }

    // place into chunk-sorted LDS order
    #pragma unroll
    for (int r = 0; r < EPT; ++r) {
        if (br[r] != 0xFFFF) {
            unsigned b = br[r];
            unsigned slot = lscan[b] - lhist[b] + rr[r];
            sbuf[slot] = pr[r];
            sbkt[slot] = (unsigned short)b;
        }
    }
    __syncthreads();

    // coalesced write-out per bucket run
    for (int slot = t; slot < nval; slot += 256) {
        unsigned p = sbuf[slot];
        unsigned b = sbkt[slot];
        unsigned lst = lscan[b] - lhist[b];
        srtp[gbase[b] + ((unsigned)slot - lst)] = p;
    }
}

// ---------- fused CSR build + per-row src sort + per-block degree histogram ----------
// LDS cut to ~40KB (no raw-pair buffer; segment re-read from L2-warm global) -> 4 blocks/CU.
__global__ __launch_bounds__(256)
void build_kernel(unsigned* __restrict__ srtp, const unsigned* __restrict__ bcur,
                  int* __restrict__ row_start, int* __restrict__ row_end,
                  unsigned* __restrict__ dhb) {
    __shared__ int      sdst[BCAP];      // 36 KB row-grouped srcs
    __shared__ unsigned ldeg[256];
    __shared__ unsigned lsc[256];
    __shared__ int      lcur[256];
    __shared__ unsigned ldh[DBIN];       // block-local degree histogram
    const int b = blockIdx.x;
    const int t = threadIdx.x;
    const int segbase = b * BCAP;
    const int cntb = min((int)bcur[b] - segbase, BCAP);

    ldeg[t] = 0u;
    if (t < DBIN) ldh[t] = 0u;
    __syncthreads();
    for (int e = t; e < cntb; e += 256)
        atomicAdd(&ldeg[srtp[segbase + e] >> 17], 1u);
    __syncthreads();
    lsc[t] = ldeg[t];
    __syncthreads();
    for (int off = 1; off < 256; off <<= 1) {
        unsigned v = (t >= off) ? lsc[t - off] : 0u;
        __syncthreads();
        lsc[t] += v;
        __syncthreads();
    }
    int excl = (int)(lsc[t] - ldeg[t]);
    int node = (b << 8) + t;
    if (node < N_NODES) {
        row_start[node] = segbase + excl;
        row_end[node]   = segbase + excl + (int)ldeg[t];
        atomicAdd(&ldh[min((int)ldeg[t], DBIN - 1)], 1u);   // LDS only
    }
    lcur[t] = excl;
    __syncthreads();
    // plain store of block histogram -- NO global atomics
    if (t < DBIN) dhb[(size_t)b * DBIN + t] = ldh[t];
    // second pass over the (L2-warm) segment: scatter into row-grouped order
    for (int e = t; e < cntb; e += 256) {
        unsigned p = srtp[segbase + e];
        int pos = atomicAdd(&lcur[p >> 17], 1);
        sdst[pos] = (int)(p & 0x1FFFFu);
    }
    __syncthreads();

    // per-wave bitonic sort of each row by src (len<=64; longer rows left as-is)
    const int wave = t >> 6, lane = t & 63;
    for (int n = wave; n < 256; n += 4) {
        int len = (int)ldeg[n];
        if (len < 2 || len > 64) continue;
        int lofs = (int)(lsc[n] - ldeg[n]);
        int v = (lane < len) ? sdst[lofs + lane] : 0x7FFFFFFF;
        #pragma unroll
        for (int k = 2; k <= 64; k <<= 1) {
            #pragma unroll
            for (int j = k >> 1; j > 0; j >>= 1) {
                int pv = __shfl_xor(v, j, 64);
                bool up    = (lane & k) == 0;
                bool lower = (lane & j) == 0;
                int mn = min(v, pv), mx = max(v, pv);
                v = (up == lower) ? mn : mx;
            }
        }
        if (lane < len) sdst[lofs + lane] = v;
    }
    __syncthreads();
    for (int e = t; e < cntb; e += 256)
        srtp[segbase + e] = (unsigned)sdst[e];
}

// ---------- per-bin exclusive prefix over blocks (atomic-free counting sort, pass 2) ----------
__global__ __launch_bounds__(512)
void pscan_kernel(unsigned* __restrict__ dhb, unsigned* __restrict__ dh) {
    __shared__ unsigned s[512];
    const int bin = blockIdx.x;
    const int t = threadIdx.x;
    unsigned v = (t < NBKT) ? dhb[(size_t)t * DBIN + bin] : 0u;
    s[t] = v;
    __syncthreads();
    for (int off = 1; off < 512; off <<= 1) {
        unsigned add = (t >= off) ? s[t - off] : 0u;
        __syncthreads();
        s[t] += add;
        __syncthreads();
    }
    if (t < NBKT) dhb[(size_t)t * DBIN + bin] = s[t] - v;   // exclusive prefix
    if (t == 511) dh[bin] = s[511];                          // bin total
}

// ---------- degree-bin base scan (descending degree) ----------
__global__ __launch_bounds__(DBIN)
void degscan_kernel(const unsigned* __restrict__ dh, unsigned* __restrict__ dcur) {
    __shared__ unsigned s[DBIN];
    const int t = threadIdx.x;               // scan position over reversed bins
    unsigned v = dh[DBIN - 1 - t];
    s[t] = v;
    __syncthreads();
    for (int off = 1; off < DBIN; off <<= 1) {
        unsigned add = (t >= off) ? s[t - off] : 0u;
        __syncthreads();
        s[t] += add;
        __syncthreads();
    }
    dcur[DBIN - 1 - t] = s[t] - v;           // exclusive prefix, descending-degree order
}

// ---------- scatter nodes into degree-descending permutation (NO global atomics) ----------
__global__ __launch_bounds__(256)
void degscatter_kernel(const int* __restrict__ row_start, const int* __restrict__ row_end,
                       const unsigned* __restrict__ dcur, const unsigned* __restrict__ dhb,
                       int* __restrict__ perm) {
    __shared__ unsigned lh[DBIN];
    const int t = threadIdx.x;
    const int blk = blockIdx.x;
    const int i = blk * 256 + t;
    if (t < DBIN) lh[t] = 0u;
    __syncthreads();
    if (i < N_NODES) {
        int d = min(row_end[i] - row_start[i], DBIN - 1);
        unsigned rank = atomicAdd(&lh[d], 1u);           // LDS rank within block's bin
        perm[dcur[d] + dhb[(size_t)blk * DBIN + d] + rank] = i;
    }
}

// ---------- fused node linear: q = (x@Wq+bq)*scale (fp32); kv bf16 interleaved; sk fp32 ----------
// kv row layout (per node, 2*OUT bf16): [k0..3 v0..3 k4..7 v4..7 ...]
template <int IN, int OUT>
__global__ __launch_bounds__(256)
void lin_kernel(const float* __restrict__ x,
                const float* __restrict__ Wq, const float* __restrict__ bq,
                const float* __restrict__ Wk, const float* __restrict__ bk,
                const float* __restrict__ Wv, const float* __restrict__ bv,
                const float* __restrict__ Ws, const float* __restrict__ bs,
                float scale,
                float* __restrict__ q, unsigned short* __restrict__ kv,
                float* __restrict__ sk, int n)
{
    __shared__ float w[4 * IN * OUT];
    __shared__ float b[4 * OUT];
    for (int t = threadIdx.x; t < IN * OUT; t += blockDim.x) {
        w[t]            = Wq[t];
        w[IN*OUT + t]   = Wk[t];
        w[2*IN*OUT + t] = Wv[t];
        w[3*IN*OUT + t] = Ws[t];
    }
    for (int t = threadIdx.x; t < OUT; t += blockDim.x) {
        b[t]         = bq[t];
        b[OUT + t]   = bk[t];
        b[2*OUT + t] = bv[t];
        b[3*OUT + t] = bs[t];
    }
    __syncthreads();

    for (int i = blockIdx.x * blockDim.x + threadIdx.x; i < n;
         i += gridDim.x * blockDim.x) {
        float xi[IN];
        #pragma unroll
        for (int r = 0; r < IN; ++r) xi[r] = x[(size_t)i * IN + r];

        #pragma unroll
        for (int j = 0; j < OUT; ++j) {
            float aq = b[j], ak = b[OUT + j], av = b[2*OUT + j], as = b[3*OUT + j];
            #pragma unroll
            for (int r = 0; r < IN; ++r) {
                float xr = xi[r];
                aq += xr * w[r*OUT + j];
                ak += xr * w[IN*OUT + r*OUT + j];
                av += xr * w[2*IN*OUT + r*OUT + j];
                as += xr * w[3*IN*OUT + r*OUT + j];
            }
            int c = j >> 2, r4 = j & 3;
            q[(size_t)i * OUT + j]                  = aq * scale;
            kv[(size_t)i * 2 * OUT + c * 8 + r4]     = f2bf(ak);
            kv[(size_t)i * 2 * OUT + c * 8 + 4 + r4] = f2bf(av);
            sk[(size_t)i * OUT + j]                 = as;
        }
    }
}

// ---------- fused per-node attention: degree-permuted nodes, 1 load/edge/lane ----------
template <int D, bool POOL>
__global__ __launch_bounds__(256)
void fused_attn_kernel(const float* __restrict__ q, const unsigned short* __restrict__ kv,
                       const float* __restrict__ sk,
                       const int* __restrict__ row_start, const int* __restrict__ row_end,
                       const unsigned* __restrict__ sorted_src,
                       const int* __restrict__ perm,
                       const int* __restrict__ b32, const long long* __restrict__ b64,
                       const int* __restrict__ flag,
                       float* __restrict__ h, float* __restrict__ pool,
                       float* __restrict__ cnt)
{
    constexpr int L = D / 4;
    const int gpb = 256 / L;
    const int lj = threadIdx.x & (L - 1);
    int g = blockIdx.x * gpb + threadIdx.x / L;
    if (g >= N_NODES) return;
    const int i = perm[g];

    const float4 qj = *(const float4*)(q + (size_t)i * D + lj * 4);
    const int beg = row_start[i], end = row_end[i];

    float m = -INFINITY, denom = 0.f;
    float4 acc = make_float4(0.f, 0.f, 0.f, 0.f);

    if (beg < end) {
        const int last = end - 1;

        int s0 = (int)sorted_src[min(beg + 0, last)];
        int s1 = (int)sorted_src[min(beg + 1, last)];
        int s2 = (int)sorted_src[min(beg + 2, last)];
        int s3 = (int)sorted_src[min(beg + 3, last)];
        uint4 A0 = ((const uint4*)(kv + (size_t)s0 * (2 * D)))[lj];
        uint4 A1 = ((const uint4*)(kv + (size_t)s1 * (2 * D)))[lj];
        uint4 B0 = ((const uint4*)(kv + (size_t)s2 * (2 * D)))[lj];
        uint4 B1 = ((const uint4*)(kv + (size_t)s3 * (2 * D)))[lj];

        for (int e = beg; e < end; e += 4) {
            // ---- half 1: edges e, e+1 from A; refill A with e+4, e+5 ----
            {
                int sn0 = (int)sorted_src[min(e + 4, last)];
                int sn1 = (int)sorted_src[min(e + 5, last)];
                float k0,k1,k2,k3, l0,l1,l2,l3;
                unpack2(A0.x, k0, k1); unpack2(A0.y, k2, k3);
                unpack2(A1.x, l0, l1); unpack2(A1.y, l2, l3);
                float pa = k0*qj.x + k1*qj.y + k2*qj.z + k3*qj.w;
                float pb = l0*qj.x + l1*qj.y + l2*qj.z + l3*qj.w;
                #pragma unroll
                for (int off = L / 2; off; off >>= 1) {
                    pa += __shfl_xor(pa, off, L);
                    pb += __shfl_xor(pb, off, L);
                }
                if (e + 1 > last) pb = -INFINITY;
                float mn = fmaxf(m, fmaxf(pa, pb));
                float so = __expf(m - mn);
                float w0 = __expf(pa - mn);
                float w1 = __expf(pb - mn);
                float u0,u1,u2,u3, t0,t1,t2,t3;
                unpack2(A0.z, u0, u1); unpack2(A0.w, u2, u3);
                unpack2(A1.z, t0, t1); unpack2(A1.w, t2, t3);
                denom = denom * so + w0 + w1;
                acc.x = acc.x * so + w0 * u0 + w1 * t0;
                acc.y = acc.y * so + w0 * u1 + w1 * t1;
                acc.z = acc.z * so + w0 * u2 + w1 * t2;
                acc.w = acc.w * so + w0 * u3 + w1 * t3;
                m = mn;
                A0 = ((const uint4*)(kv + (size_t)sn0 * (2 * D)))[lj];
                A1 = ((const uint4*)(kv + (size_t)sn1 * (2 * D)))[lj];
            }
            // ---- half 2: edges e+2, e+3 from B; refill B with e+6, e+7 ----
            {
                int sn0 = (int)sorted_src[min(e + 6, last)];
                int sn1 = (int)sorted_src[min(e + 7, last)];
                float k0,k1,k2,k3, l0,l1,l2,l3;
                unpack2(B0.x, k0, k1); unpack2(B0.y, k2, k3);
                unpack2(B1.x, l0, l1); unpack2(B1.y, l2, l3);
                float pa = k0*qj.x + k1*qj.y + k2*qj.z + k3*qj.w;
                float pb = l0*qj.x + l1*qj.y + l2*qj.z + l3*qj.w;
                #pragma unroll
                for (int off = L / 2; off; off >>= 1) {
                    pa += __shfl_xor(pa, off, L);
                    pb += __shfl_xor(pb, off, L);
                }
                if (e + 2 > last) pa = -INFINITY;
                if (e + 3 > last) pb = -INFINITY;
                float mn = fmaxf(m, fmaxf(pa, pb));   // mn == m if both invalid
                float so = __expf(m - mn);
                float w0 = __expf(pa - mn);
                float w1 = __expf(pb - mn);
                float u0,u1,u2,u3, t0,t1,t2,t3;
                unpack2(B0.z, u0, u1); unpack2(B0.w, u2, u3);
                unpack2(B1.z, t0, t1); unpack2(B1.w, t2, t3);
                denom = denom * so + w0 + w1;
                acc.x = acc.x * so + w0 * u0 + w1 * t0;
                acc.y = acc.y * so + w0 * u1 + w1 * t1;
                acc.z = acc.z * so + w0 * u2 + w1 * t2;
                acc.w = acc.w * so + w0 * u3 + w1 * t3;
                m = mn;
                B0 = ((const uint4*)(kv + (size_t)sn0 * (2 * D)))[lj];
                B1 = ((const uint4*)(kv + (size_t)sn1 * (2 * D)))[lj];
            }
        }
    }

    float dn = 1.f / fmaxf(denom, 1e-16f);
    const float4 skv = *(const float4*)(sk + (size_t)i * D + lj * 4);
    float4 o;
    o.x = fmaxf(acc.x * dn + skv.x, 0.f);
    o.y = fmaxf(acc.y * dn + skv.y, 0.f);
    o.z = fmaxf(acc.z * dn + skv.z, 0.f);
    o.w = fmaxf(acc.w * dn + skv.w, 0.f);

    if (POOL) {
        int b = (*flag) ? (int)b64[i] : b32[i];
        float* pb = pool + b * 32 + lj * 4;
        atomicAdd(pb + 0, o.x);
        atomicAdd(pb + 1, o.y);
        atomicAdd(pb + 2, o.z);
        atomicAdd(pb + 3, o.w);
        if (lj == 0) atomicAdd(&cnt[b], 1.f);
    } else {
        *(float4*)(h + (size_t)i * D + lj * 4) = o;
    }
}

// ---------- final MLP: out = relu(mean @ Wf1 + bf1) @ Wf2 + bf2 ----------
__global__ __launch_bounds__(64)
void mlp_kernel(const float* __restrict__ pool, const float* __restrict__ cnt,
                const float* __restrict__ Wf1, const float* __restrict__ bf1,
                const float* __restrict__ Wf2, const float* __restrict__ bf2,
                float* __restrict__ out)
{
    int g = blockIdx.x;
    int h = threadIdx.x;            // 64 threads = 64 hidden units
    __shared__ float m[32];
    if (h < 32) {
        float c = fmaxf(cnt[g], 1.f);
        m[h] = pool[g * 32 + h] / c;
    }
    __syncthreads();
    float acc = bf1[h];
    #pragma unroll
    for (int r = 0; r < 32; ++r) acc += m[r] * Wf1[r * 64 + h];
    float hid = fmaxf(acc, 0.f);
    float c = hid * Wf2[h];
    #pragma unroll
    for (int off = 32; off; off >>= 1) c += __shfl_xor(c, off, 64);
    if (h == 0) out[g] = c + bf2[0];
}

extern "C" void kernel_launch(void* const* d_in, const int* in_sizes, int n_in,
                              void* d_out, int out_size, void* d_ws, size_t ws_size,
                              hipStream_t stream) {
    const float* x = (const float*)d_in[0];
    const void*  edge_index = d_in[1];
    const void*  batch      = d_in[2];
    const float* Wq1 = (const float*)d_in[3];  const float* bq1 = (const float*)d_in[4];
    const float* Wk1 = (const float*)d_in[5];  const float* bk1 = (const float*)d_in[6];
    const float* Wv1 = (const float*)d_in[7];  const float* bv1 = (const float*)d_in[8];
    const float* Ws1 = (const float*)d_in[9];  const float* bs1 = (const float*)d_in[10];
    const float* Wq2 = (const float*)d_in[11]; const float* bq2 = (const float*)d_in[12];
    const float* Wk2 = (const float*)d_in[13]; const float* bk2 = (const float*)d_in[14];
    const float* Wv2 = (const float*)d_in[15]; const float* bv2 = (const float*)d_in[16];
    const float* Ws2 = (const float*)d_in[17]; const float* bs2 = (const float*)d_in[18];
    const float* Wf1 = (const float*)d_in[19]; const float* bf1 = (const float*)d_in[20];
    const float* Wf2 = (const float*)d_in[21]; const float* bf2 = (const float*)d_in[22];
    float* out = (float*)d_out;

    // ---------------- workspace layout (~60 MB) ----------------
    char* ws = (char*)d_ws;
    size_t off = 0;
    auto carve = [&](size_t bytes) {
        char* p = ws + off;
        off = (off + bytes + 255) & ~(size_t)255;
        return p;
    };
    int*            flag     = (int*)            carve(16);
    int*            row_start= (int*)            carve((size_t)N_NODES * 4);
    int*            row_end  = (int*)            carve((size_t)N_NODES * 4);
    unsigned*       bcur     = (unsigned*)       carve((size_t)NBKT * 4);
    float*          pool     = (float*)          carve((size_t)N_GRAPHS * 32 * 4);
    float*          cnt      = (float*)          carve((size_t)N_GRAPHS * 4);
    unsigned*       dh       = (unsigned*)       carve((size_t)DBIN * 4);
    unsigned*       dcur     = (unsigned*)       carve((size_t)DBIN * 4);
    unsigned*       dhb      = (unsigned*)       carve((size_t)NBKT * DBIN * 4);
    int*            perm     = (int*)            carve((size_t)N_NODES * 4);
    unsigned*       srtp     = (unsigned*)       carve((size_t)NBKT * BCAP * 4);  // padded pairs -> sorted srcs
    float*          qb       = (float*)          carve((size_t)N_NODES * 32 * 4);
    unsigned short* kvb      = (unsigned short*) carve((size_t)N_NODES * 64 * 2);
    float*          skb      = (float*)          carve((size_t)N_NODES * 32 * 4);
    float*          h1       = (float*)          carve((size_t)N_NODES * 16 * 4);
    (void)ws_size; (void)in_sizes; (void)n_in; (void)out_size;

    const int* ei32 = (const int*)edge_index;
    const long long* ei64 = (const long long*)edge_index;
    const int* b32 = (const int*)batch;
    const long long* b64 = (const long long*)batch;

    const dim3 blk(256);

    // ---- CSR build: padded buckets, single partition pass, fused build+rowsort ----
    init_kernel<<<(N_GRAPHS * 32 + 255) / 256, blk, 0, stream>>>(ei64, flag, bcur, pool, cnt);
    partition_kernel<<<(N_EDGES + PCHUNK - 1) / PCHUNK, blk, 0, stream>>>(
        ei32, ei64, flag, bcur, srtp);
    build_kernel<<<NBKT, blk, 0, stream>>>(srtp, bcur, row_start, row_end, dhb);
    pscan_kernel<<<DBIN, 512, 0, stream>>>(dhb, dh);
    degscan_kernel<<<1, DBIN, 0, stream>>>(dh, dcur);
    degscatter_kernel<<<NBKT, blk, 0, stream>>>(row_start, row_end, dcur, dhb, perm);

    // ---- layer 1 (11 -> 16): L=4 lanes/node, 64 nodes/block ----
    lin_kernel<11, 16><<<(N_NODES + 255) / 256, blk, 0, stream>>>(
        x, Wq1, bq1, Wk1, bk1, Wv1, bv1, Ws1, bs1, 0.25f,
        qb, kvb, skb, N_NODES);
    fused_attn_kernel<16, false><<<(N_NODES + 63) / 64, blk, 0, stream>>>(
        qb, kvb, skb, row_start, row_end, srtp, perm, b32, b64, flag, h1, pool, cnt);

    // ---- layer 2 (16 -> 32): L=8 lanes/node, 32 nodes/block; pooling fused ----
    lin_kernel<16, 32><<<(N_NODES + 255) / 256, blk, 0, stream>>>(
        h1, Wq2, bq2, Wk2, bk2, Wv2, bv2, Ws2, bs2, 0.17677669529663688f,
        qb, kvb, skb, N_NODES);
    fused_attn_kernel<32, true><<<(N_NODES + 31) / 32, blk, 0, stream>>>(
        qb, kvb, skb, row_start, row_end, srtp, perm, b32, b64, flag, nullptr, pool, cnt);

    // ---- MLP head ----
    mlp_kernel<<<N_GRAPHS, 64, 0, stream>>>(pool, cnt, Wf1, bf1, Wf2, bf2, out);
}